// Round 11
// baseline (1005.158 us; speedup 1.0000x reference)
//
#include <hip/hip_runtime.h>
#include <stdint.h>

// ---------------------------------------------------------------------------
// Linear (kernelized) attention, B=4 L=4096 D=1024 H=16 M=64, fp32 in/out.
//   1. k_prep_w4: 4 weight transposes -> bf16 WT[out][in] (MFMA B layout)
//   2. k_proj3  : ONE dispatch, grid (64,4,3), z = {q,k,v}.  Fused fp32->bf16
//                 + 256x256/BK=64 MFMA GEMM, 2-barrier loop, 64 KiB LDS
//                 (single-buffered staging; epilogue transpose in two
//                 128-row passes) -> 2 blocks/CU co-residency (768 blocks).
//                 mode 0: q=relu(X Wq+b)+eps -> [B][L][1024]
//                 mode 1: k -> kt [B][1024][L]   mode 2: v -> vt [B][16][80][L]
//   3. k_gemm256: round-8 8-phase GEMM: out = avn.WoT + bo (fp32)
//      k_init_vt: vt row 64 = 1.0 (kvs col 64 = ks_sum), 65..79 = 0
//   4. k_kvs    : per (b,h) kvs[64 m][80 d'] += kt . vt^T  (fp32 atomics)
//   5. k_kvs_t  : kvs fp32 -> bav bf16 [bh][80][64] (transpose)
//   6. k_av     : C[l][80] = q . bav^T; col 64 = norm; avn = C/norm (bf16)
// ---------------------------------------------------------------------------

typedef __bf16 bf16;
typedef __bf16 bf16x4 __attribute__((ext_vector_type(4)));
typedef __bf16 bf16x8 __attribute__((ext_vector_type(8)));
typedef float f32x4 __attribute__((ext_vector_type(4)));

#define MFMA_(a, b, c) __builtin_amdgcn_mfma_f32_16x16x32_bf16((a), (b), (c), 0, 0, 0)

static constexpr int BB   = 4;
static constexpr int LSEQ = 4096;
static constexpr int DIM  = 1024;   // D == H*M
static constexpr int HH   = 16;
static constexpr float EPSF = 0.001f;

// ---- async global->LDS, 16B per lane, wave-uniform LDS base ---------------
__device__ __forceinline__ void gload16(bf16* lds, const bf16* g) {
  __builtin_amdgcn_global_load_lds(
      (const __attribute__((address_space(1))) void*)g,
      (__attribute__((address_space(3))) void*)lds, 16, 0, 0);
}

// ---------------- weight transpose: fp32 [1024][1024] -> bf16 out[c][r] ----
__global__ void k_prep_w4(const float* __restrict__ W0, const float* __restrict__ W1,
                          const float* __restrict__ W2, const float* __restrict__ W3,
                          bf16* __restrict__ T0, bf16* __restrict__ T1,
                          bf16* __restrict__ T2, bf16* __restrict__ T3) {
  const float* W; bf16* T;
  switch (blockIdx.z) {
    case 0:  W = W0; T = T0; break;
    case 1:  W = W1; T = T1; break;
    case 2:  W = W2; T = T2; break;
    default: W = W3; T = T3; break;
  }
  __shared__ float t[32][33];
  const int tx = threadIdx.x & 31, ty = threadIdx.x >> 5;   // 32 x 8
  const int r0 = blockIdx.x * 32, c0 = blockIdx.y * 32;
#pragma unroll
  for (int j = 0; j < 32; j += 8)
    t[ty + j][tx] = W[(size_t)(r0 + ty + j) * DIM + c0 + tx];
  __syncthreads();
#pragma unroll
  for (int j = 0; j < 32; j += 8)
    T[(size_t)(c0 + ty + j) * DIM + r0 + tx] = (bf16)t[tx][ty + j];
}

// ---------------- vt rows 64..79: row 64 = ones, rest zeros ----------------
__global__ void k_init_vt(bf16* __restrict__ vt) {
  const int c = blockIdx.x * 256 + threadIdx.x;
  const int l8 = c & 511;
  const int r  = (c >> 9) & 15;
  const int bh = c >> 13;
  const bf16 val = (r == 0) ? (bf16)1.0f : (bf16)0.0f;
  bf16x8 o;
#pragma unroll
  for (int j = 0; j < 8; ++j) o[j] = val;
  *reinterpret_cast<bf16x8*>(vt + ((size_t)bh * 80 + 64 + r) * LSEQ + l8 * 8) = o;
}

// ===========================================================================
// k_proj3: one dispatch for q/k/v.  Fused cvt + 256x256/BK=64 GEMM,
// 64 KiB LDS (2 blocks/CU), two-pass epilogue transpose.
// ===========================================================================
__global__ __launch_bounds__(512, 4) void k_proj3(
    const float* __restrict__ Xq, const float* __restrict__ Xk, const float* __restrict__ Xv,
    const bf16* __restrict__ WQT, const bf16* __restrict__ WKT, const bf16* __restrict__ WVT,
    const float* __restrict__ bq, const float* __restrict__ bk, const float* __restrict__ bv,
    bf16* __restrict__ Qb, bf16* __restrict__ KT, bf16* __restrict__ VT) {
  __shared__ __align__(16) bf16 SH[32768];      // 64 KiB
  bf16* As = SH;                                // 16384: A tile 256x64
  bf16* Bs = SH + 16384;                        // 16384: B tile 256x64
  const int mode = blockIdx.z;                  // 0=q 1=k 2=v
  const float* X    = (mode == 0) ? Xq  : (mode == 1) ? Xk  : Xv;
  const bf16*  WT   = (mode == 0) ? WQT : (mode == 1) ? WKT : WVT;
  const float* bias = (mode == 0) ? bq  : (mode == 1) ? bk  : bv;
  bf16*        outp = (mode == 0) ? Qb  : (mode == 1) ? KT  : VT;

  const int tid = threadIdx.x;
  const int lane = tid & 63, w = tid >> 6;      // 8 waves
  const int wm = w >> 2, wn = w & 3;            // 2 x 4 wave grid
  const int lr = lane & 15, lk = (lane >> 4) & 3;
  const int n0 = blockIdx.x * 256, c0 = blockIdx.y * 256;
  const int swz = (lr & 7) * 8;
  const int col0 = (lk * 8) ^ swz;
  const int col1 = (lk * 8 + 32) ^ swz;
  const int srow = lane >> 3;
  const int scol = (((lane & 7) ^ ((lane >> 3) & 7)) * 8);
  const float* Xb = X + (size_t)n0 * DIM;
  const bf16* Bb = WT + (size_t)c0 * DIM;

  f32x4 acc[8][4] = {};
  f32x4 af[8];

  // prologue: A tile 0 -> regs
#pragma unroll
  for (int j = 0; j < 8; ++j) {
    const int idx = tid + j * 512, row = idx >> 4, c4 = idx & 15;
    af[j] = *reinterpret_cast<const f32x4*>(Xb + (size_t)row * DIM + c4 * 4);
  }

  for (int ks = 0; ks < 16; ++ks) {
    const int k0 = ks * 64;
    __syncthreads();                            // LDS free (prev reads done)
    // stage B tile ks (4 gload16 per wave, pre-swizzled source)
#pragma unroll
    for (int rr = 0; rr < 4; ++rr) {
      const int row = (rr * 8 + w) * 8 + srow;
      gload16(Bs + (rr * 8 + w) * 512, Bb + (size_t)row * DIM + k0 + scol);
    }
    // write A tile ks from regs (fp32 -> bf16, swizzled)
#pragma unroll
    for (int j = 0; j < 8; ++j) {
      const int idx = tid + j * 512, row = idx >> 4, c4 = idx & 15;
      bf16x4 o;
      o[0] = (bf16)af[j][0]; o[1] = (bf16)af[j][1];
      o[2] = (bf16)af[j][2]; o[3] = (bf16)af[j][3];
      *reinterpret_cast<bf16x4*>(
          &As[row * 64 + ((((c4 >> 1) ^ (row & 7)) << 3) | ((c4 & 1) << 2))]) = o;
    }
    __syncthreads();                            // drains B vmcnt + A writes
    // issue next A tile's loads (fly under the MFMA block = T14)
    if (ks < 15) {
#pragma unroll
      for (int j = 0; j < 8; ++j) {
        const int idx = tid + j * 512, row = idx >> 4, c4 = idx & 15;
        af[j] = *reinterpret_cast<const f32x4*>(Xb + (size_t)row * DIM + k0 + 64 + c4 * 4);
      }
    }
    // compute: 64 MFMA
    bf16x8 a[8][2], b[4][2];
#pragma unroll
    for (int f = 0; f < 8; ++f) {
      a[f][0] = *reinterpret_cast<const bf16x8*>(&As[(wm * 128 + f * 16 + lr) * 64 + col0]);
      a[f][1] = *reinterpret_cast<const bf16x8*>(&As[(wm * 128 + f * 16 + lr) * 64 + col1]);
    }
#pragma unroll
    for (int cb = 0; cb < 4; ++cb) {
      b[cb][0] = *reinterpret_cast<const bf16x8*>(&Bs[(wn * 64 + cb * 16 + lr) * 64 + col0]);
      b[cb][1] = *reinterpret_cast<const bf16x8*>(&Bs[(wn * 64 + cb * 16 + lr) * 64 + col1]);
    }
#pragma unroll
    for (int kk = 0; kk < 2; ++kk)
#pragma unroll
      for (int f = 0; f < 8; ++f)
#pragma unroll
        for (int cb = 0; cb < 4; ++cb)
          acc[f][cb] = MFMA_(a[f][kk], b[cb][kk], acc[f][cb]);
  }

  // ---------------- two-pass epilogue (64 KiB) ------------------------------
  float bvv[4];
#pragma unroll
  for (int cb = 0; cb < 4; ++cb) bvv[cb] = bias[c0 + wn * 64 + cb * 16 + lr];
  const int bidx = n0 >> 12;
  const int l0 = n0 & (LSEQ - 1);

  if (mode == 0) {
    // pass p: rows p*128..p*128+127 of [l][c], c-16B-blocks XOR'd by l&7
#pragma unroll
    for (int p = 0; p < 2; ++p) {
      __syncthreads();
      if (wm == p) {
#pragma unroll
        for (int f = 0; f < 8; ++f)
#pragma unroll
          for (int cb = 0; cb < 4; ++cb) {
            const int cl = wn * 64 + cb * 16 + lr;
#pragma unroll
            for (int r = 0; r < 4; ++r) {
              float x = acc[f][cb][r] + bvv[cb];
              x = fmaxf(x, 0.f) + EPSF;
              const int ll = f * 16 + lk * 4 + r;              // local 0..127
              SH[ll * 256 + ((((cl >> 3) ^ (ll & 7)) << 3) | (cl & 7))] = (bf16)x;
            }
          }
      }
      __syncthreads();
#pragma unroll
      for (int it = 0; it < 8; ++it) {
        const int chunk = it * 512 + tid;
        const int row = chunk >> 5, blk = chunk & 31;
        const bf16x8 v = *reinterpret_cast<const bf16x8*>(&SH[row * 256 + ((blk ^ (row & 7)) << 3)]);
        *reinterpret_cast<bf16x8*>(outp + (size_t)(n0 + p * 128 + row) * DIM + c0 + blk * 8) = v;
      }
    }
  } else {
    // pass p: [c 256][l 128] slab (l = l0+p*128..), l-16B-blocks XOR'd by c&7
#pragma unroll
    for (int p = 0; p < 2; ++p) {
      __syncthreads();
      if (wm == p) {
#pragma unroll
        for (int f = 0; f < 8; ++f)
#pragma unroll
          for (int cb = 0; cb < 4; ++cb) {
            const int cl = wn * 64 + cb * 16 + lr;
            const int ll = f * 16 + lk * 4;                    // local 0..124
            bf16x4 o;
#pragma unroll
            for (int r = 0; r < 4; ++r) {
              float x = acc[f][cb][r] + bvv[cb];
              if (mode == 1) x = fmaxf(x, 0.f) + EPSF;
              o[r] = (bf16)x;
            }
            *reinterpret_cast<bf16x4*>(
                &SH[cl * 128 + ((((ll >> 3) ^ (cl & 7)) << 3) | (ll & 7))]) = o;
          }
      }
      __syncthreads();
#pragma unroll
      for (int it = 0; it < 8; ++it) {
        const int chunk = it * 512 + tid;
        const int row = chunk >> 4, blk = chunk & 15;          // row = local c
        const bf16x8 v = *reinterpret_cast<const bf16x8*>(&SH[row * 128 + ((blk ^ (row & 7)) << 3)]);
        const int cg = c0 + row;
        size_t rowbase;
        if (mode == 1) rowbase = (size_t)bidx * 1024 + cg;                           // kt [b][c][L]
        else           rowbase = ((size_t)(bidx * HH + (cg >> 6)) * 80 + (cg & 63)); // vt [b][h][80][L]
        *reinterpret_cast<bf16x8*>(outp + rowbase * LSEQ + l0 + p * 128 + blk * 8) = v;
      }
    }
  }
}

// ===========================================================================
// k_gemm256 (round-8 8-phase): out = A . WT^T + bias  (fp32)
// ===========================================================================
__device__ __forceinline__ void stage_half(bf16* As0, bf16* Bs0,
                                           const bf16* Ab, const bf16* Bb,
                                           int h, int w, int srow, int scol) {
  const int t = h >> 2, reg = h & 3, buf = t & 1;
  bf16* lds = ((reg < 2) ? As0 : Bs0) + buf * 16384 + (reg & 1) * 8192;
  const bf16* g = (reg < 2) ? Ab : Bb;
  const int rbase = (reg & 1) * 128;
#pragma unroll
  for (int rr = 0; rr < 2; ++rr) {
    const int row = rbase + (rr * 8 + w) * 8 + srow;
    gload16(lds + (rr * 8 + w) * 512, g + (size_t)row * DIM + t * 64 + scol);
  }
}

#define LDA(d, g, f)                                                                              \
  a[d][0] = *reinterpret_cast<const bf16x8*>(&As0[(g) * 16384 + (wm * 128 + (f) * 16 + lr) * 64 + col0]); \
  a[d][1] = *reinterpret_cast<const bf16x8*>(&As0[(g) * 16384 + (wm * 128 + (f) * 16 + lr) * 64 + col1]);
#define LDB(d, g, c)                                                                              \
  b[d][0] = *reinterpret_cast<const bf16x8*>(&Bs0[(g) * 16384 + (wn * 64 + (c) * 16 + lr) * 64 + col0]); \
  b[d][1] = *reinterpret_cast<const bf16x8*>(&Bs0[(g) * 16384 + (wn * 64 + (c) * 16 + lr) * 64 + col1]);
#define MM(fi, ci, fo, co)                                                                        \
  acc[fo][co] = MFMA_(a[fi][0], b[ci][0], acc[fo][co]);                                           \
  acc[fo][co] = MFMA_(a[fi][1], b[ci][1], acc[fo][co]);

#define PHASE(g, q, pidx)                                                                         \
  {                                                                                               \
    if ((q) == 0) { LDA(0, g, 0) LDA(1, g, 1) LDA(2, g, 2) LDA(3, g, 3)                           \
                    LDB(0, g, 0) LDB(1, g, 1) }                                                   \
    else if ((q) == 1) { LDB(0, g, 2) LDB(1, g, 3) }                                              \
    else if ((q) == 2) { LDA(0, g, 4) LDA(1, g, 5) LDA(2, g, 6) LDA(3, g, 7) }                    \
    else { LDB(0, g, 0) LDB(1, g, 1) }                                                            \
    const int hh = 8 * i + 5 + (pidx);                                                            \
    if (hh < 64) stage_half(As0, Bs0, Ab, Bb, hh, w, srow, scol);                                 \
    if ((pidx) == 3 || (pidx) == 7) {                                                             \
      if (i < 7) { asm volatile("s_waitcnt vmcnt(2)" ::: "memory"); }                             \
      else       { asm volatile("s_waitcnt vmcnt(0)" ::: "memory"); }                             \
    }                                                                                             \
    __builtin_amdgcn_sched_barrier(0);                                                            \
    __builtin_amdgcn_s_barrier();                                                                 \
    __builtin_amdgcn_sched_barrier(0);                                                            \
    __builtin_amdgcn_s_setprio(1);                                                                \
    if ((q) == 0) { MM(0, 0, 0, 0) MM(1, 0, 1, 0) MM(2, 0, 2, 0) MM(3, 0, 3, 0)                   \
                    MM(0, 1, 0, 1) MM(1, 1, 1, 1) MM(2, 1, 2, 1) MM(3, 1, 3, 1) }                 \
    else if ((q) == 1) { MM(0, 0, 0, 2) MM(1, 0, 1, 2) MM(2, 0, 2, 2) MM(3, 0, 3, 2)              \
                         MM(0, 1, 0, 3) MM(1, 1, 1, 3) MM(2, 1, 2, 3) MM(3, 1, 3, 3) }            \
    else if ((q) == 2) { MM(0, 0, 4, 2) MM(1, 0, 5, 2) MM(2, 0, 6, 2) MM(3, 0, 7, 2)              \
                         MM(0, 1, 4, 3) MM(1, 1, 5, 3) MM(2, 1, 6, 3) MM(3, 1, 7, 3) }            \
    else { MM(0, 0, 4, 0) MM(1, 0, 5, 0) MM(2, 0, 6, 0) MM(3, 0, 7, 0)                            \
           MM(0, 1, 4, 1) MM(1, 1, 5, 1) MM(2, 1, 6, 1) MM(3, 1, 7, 1) }                          \
    __builtin_amdgcn_s_setprio(0);                                                                \
    __builtin_amdgcn_sched_barrier(0);                                                            \
    __builtin_amdgcn_s_barrier();                                                                 \
    __builtin_amdgcn_sched_barrier(0);                                                            \
  }

__global__ __launch_bounds__(512, 2) void k_gemm256(const bf16* __restrict__ X,
                                                    const bf16* __restrict__ WT,
                                                    const float* __restrict__ bias,
                                                    float* __restrict__ outp) {
  __shared__ __align__(16) bf16 SH[65536];
  bf16* As0 = SH;
  bf16* Bs0 = SH + 32768;
  const int tid = threadIdx.x;
  const int lane = tid & 63, w = tid >> 6;
  const int wm = w >> 2, wn = w & 3;
  const int lr = lane & 15, lk = (lane >> 4) & 3;
  const int n0 = blockIdx.x * 256, c0 = blockIdx.y * 256;
  const int swz = (lr & 7) * 8;
  const int col0 = (lk * 8) ^ swz;
  const int col1 = (lk * 8 + 32) ^ swz;
  const int srow = lane >> 3;
  const int scol = (((lane & 7) ^ ((lane >> 3) & 7)) * 8);
  const bf16* Ab = X + (size_t)n0 * DIM;
  const bf16* Bb = WT + (size_t)c0 * DIM;

  f32x4 acc[8][4] = {};
  bf16x8 a[4][2], b[2][2];

#pragma unroll
  for (int h = 0; h < 5; ++h) stage_half(As0, Bs0, Ab, Bb, h, w, srow, scol);
  asm volatile("s_waitcnt vmcnt(2)" ::: "memory");
  __builtin_amdgcn_sched_barrier(0);
  __builtin_amdgcn_s_barrier();
  __builtin_amdgcn_sched_barrier(0);

  for (int i = 0; i < 8; ++i) {
    PHASE(0, 0, 0) PHASE(0, 1, 1) PHASE(0, 2, 2) PHASE(0, 3, 3)
    PHASE(1, 0, 4) PHASE(1, 1, 5) PHASE(1, 2, 6) PHASE(1, 3, 7)
  }

  float bvv[4];
#pragma unroll
  for (int cb = 0; cb < 4; ++cb) bvv[cb] = bias[c0 + wn * 64 + cb * 16 + lr];
#pragma unroll
  for (int f = 0; f < 8; ++f)
#pragma unroll
    for (int cb = 0; cb < 4; ++cb) {
      const int c = c0 + wn * 64 + cb * 16 + lr;
#pragma unroll
      for (int r = 0; r < 4; ++r) {
        const int row = n0 + wm * 128 + f * 16 + lk * 4 + r;
        outp[(size_t)row * DIM + c] = acc[f][cb][r] + bvv[cb];
      }
    }
}
#undef PHASE
#undef MM
#undef LDB
#undef LDA

// ---------------- kvs: per (b,h) C[64 m][80 d'] = kt . vt^T over l ---------
__global__ __launch_bounds__(256, 2) void k_kvs(const bf16* __restrict__ kt,
                                                const bf16* __restrict__ vt,
                                                float* __restrict__ kvs) {
  const int tid = threadIdx.x, lane = tid & 63, wid = tid >> 6;
  const int lr = lane & 15, lk = lane >> 4;
  const int bh = blockIdx.y;
  const int lbase = blockIdx.x * 256;       // 16 l-slices of 256
  __shared__ bf16 As[64][64];
  __shared__ bf16 Bs[80][64];
  f32x4 acc[5] = {};
  const bf16* ktb = kt + (size_t)bh * 64 * LSEQ;
  const bf16* vtb = vt + (size_t)bh * 80 * LSEQ;

  for (int ks = 0; ks < 4; ++ks) {
    const int l0 = lbase + ks * 64;
    __syncthreads();
#pragma unroll
    for (int i = 0; i < 2; ++i) {
      const int e = i * 2048 + tid * 8;
      const int row = e >> 6, col = e & 63;
      *reinterpret_cast<bf16x8*>(&As[row][col]) =
          *reinterpret_cast<const bf16x8*>(ktb + (size_t)row * LSEQ + l0 + col);
    }
#pragma unroll
    for (int i = 0; i < 2; ++i) {
      const int e = i * 2048 + tid * 8;
      const int row = e >> 6, col = e & 63;
      *reinterpret_cast<bf16x8*>(&Bs[row][col]) =
          *reinterpret_cast<const bf16x8*>(vtb + (size_t)row * LSEQ + l0 + col);
    }
    if (tid < 128) {
      const int e = 4096 + tid * 8;
      const int row = e >> 6, col = e & 63;
      *reinterpret_cast<bf16x8*>(&Bs[row][col]) =
          *reinterpret_cast<const bf16x8*>(vtb + (size_t)row * LSEQ + l0 + col);
    }
    __syncthreads();
#pragma unroll
    for (int kk = 0; kk < 2; ++kk) {
      const bf16x8 af = *reinterpret_cast<const bf16x8*>(&As[wid * 16 + lr][kk * 32 + lk * 8]);
#pragma unroll
      for (int cb = 0; cb < 5; ++cb) {
        const bf16x8 bfr = *reinterpret_cast<const bf16x8*>(&Bs[cb * 16 + lr][kk * 32 + lk * 8]);
        acc[cb] = MFMA_(af, bfr, acc[cb]);
      }
    }
  }
  float* kb = kvs + (size_t)bh * 64 * 80;
#pragma unroll
  for (int cb = 0; cb < 5; ++cb) {
    const int dcol = cb * 16 + lr;
#pragma unroll
    for (int r = 0; r < 4; ++r) {
      const int m = wid * 16 + lk * 4 + r;
      atomicAdd(kb + m * 80 + dcol, acc[cb][r]);
    }
  }
}

// ---------------- kvs fp32 [bh][64][80] -> bav bf16 [bh][80][64] -----------
__global__ void k_kvs_t(const float* __restrict__ kvs, bf16* __restrict__ bav) {
  const int bh = blockIdx.x;
  const float* src = kvs + (size_t)bh * 5120;
  bf16* dst = bav + (size_t)bh * 5120;
  for (int i = threadIdx.x; i < 5120; i += 256) {
    const int dp = i >> 6, mm = i & 63;
    dst[i] = (bf16)src[mm * 80 + dp];
  }
}

// ---------------- av: per (b,h) C[128 l][80] = q . bav^T; normalize --------
__global__ __launch_bounds__(256, 2) void k_av(const bf16* __restrict__ q,
                                               const bf16* __restrict__ bav,
                                               bf16* __restrict__ avn) {
  const int tid = threadIdx.x, lane = tid & 63, wid = tid >> 6;
  const int lr = lane & 15, lk = lane >> 4;
  const int bh = blockIdx.y, b = bh >> 4, h = bh & 15;
  const int l0 = blockIdx.x * 128;
  __shared__ bf16 As[128][64];
  __shared__ bf16 Bs[80][64];
  __shared__ float nrm[128];

  const bf16* qb = q + ((size_t)b * LSEQ + l0) * DIM + h * 64;
#pragma unroll
  for (int i = 0; i < 4; ++i) {
    const int e = i * 2048 + tid * 8;
    const int row = e >> 6, col = e & 63;
    *reinterpret_cast<bf16x8*>(&As[row][col]) =
        *reinterpret_cast<const bf16x8*>(qb + (size_t)row * DIM + col);
  }
  const bf16* bb = bav + (size_t)bh * 5120;
#pragma unroll
  for (int i = 0; i < 2; ++i) {
    const int e = i * 2048 + tid * 8;
    const int row = e >> 6, col = e & 63;
    *reinterpret_cast<bf16x8*>(&Bs[row][col]) =
        *reinterpret_cast<const bf16x8*>(bb + row * 64 + col);
  }
  if (tid < 128) {
    const int e = 4096 + tid * 8;
    const int row = e >> 6, col = e & 63;
    *reinterpret_cast<bf16x8*>(&Bs[row][col]) =
        *reinterpret_cast<const bf16x8*>(bb + row * 64 + col);
  }
  __syncthreads();

  f32x4 acc[2][5] = {};
#pragma unroll
  for (int kk = 0; kk < 2; ++kk) {
    bf16x8 af[2];
    af[0] = *reinterpret_cast<const bf16x8*>(&As[wid * 32 + lr][kk * 32 + lk * 8]);
    af[1] = *reinterpret_cast<const bf16x8*>(&As[wid * 32 + 16 + lr][kk * 32 + lk * 8]);
#pragma unroll
    for (int cb = 0; cb < 5; ++cb) {
      const bf16x8 bfr = *reinterpret_cast<const bf16x8*>(&Bs[cb * 16 + lr][kk * 32 + lk * 8]);
      acc[0][cb] = MFMA_(af[0], bfr, acc[0][cb]);
      acc[1][cb] = MFMA_(af[1], bfr, acc[1][cb]);
    }
  }
  if (lr == 0) {
#pragma unroll
    for (int rb = 0; rb < 2; ++rb)
#pragma unroll
      for (int r = 0; r < 4; ++r)
        nrm[wid * 32 + rb * 16 + lk * 4 + r] = acc[rb][4][r];
  }
  __syncthreads();
  bf16* ob = avn + ((size_t)b * LSEQ + l0) * DIM + h * 64;
#pragma unroll
  for (int rb = 0; rb < 2; ++rb) {
#pragma unroll
    for (int cb = 0; cb < 4; ++cb) {
#pragma unroll
      for (int r = 0; r < 4; ++r) {
        const int row = wid * 32 + rb * 16 + lk * 4 + r;
        const float x = acc[rb][cb][r] / nrm[row];
        ob[(size_t)row * DIM + cb * 16 + lr] = (bf16)x;
      }
    }
  }
}

// ---------------------------------------------------------------------------
extern "C" void kernel_launch(void* const* d_in, const int* in_sizes, int n_in,
                              void* d_out, int out_size, void* d_ws, size_t ws_size,
                              hipStream_t stream) {
  const float* query = (const float*)d_in[0];
  const float* key   = (const float*)d_in[1];
  const float* value = (const float*)d_in[2];
  const float* Wq    = (const float*)d_in[3];
  const float* bq    = (const float*)d_in[4];
  const float* Wk    = (const float*)d_in[5];
  const float* bk    = (const float*)d_in[6];
  const float* Wv    = (const float*)d_in[7];
  const float* bvp   = (const float*)d_in[8];
  const float* Wo    = (const float*)d_in[9];
  const float* bo    = (const float*)d_in[10];
  float* out = (float*)d_out;
  char* ws = (char*)d_ws;

  const size_t off_wqt = 0;                        // 2 MB each
  const size_t off_wkt = off_wqt + (2u << 20);
  const size_t off_wvt = off_wkt + (2u << 20);
  const size_t off_wot = off_wvt + (2u << 20);
  const size_t off_kt  = off_wot + (2u << 20);     // 33,554,432
  const size_t off_qb  = off_kt  + 33554432ull;    // 33,554,432
  const size_t off_av  = off_qb  + 33554432ull;    // 33,554,432
  const size_t off_vt  = off_av  + 33554432ull;    // 41,943,040
  const size_t off_kvs = off_vt  + 41943040ull;    //  1,310,720 (fp32)
  const size_t off_bav = off_kvs + 1310720ull;     //    655,360
  const size_t total   = off_bav + 655360ull;      // ~146 MB
  if (ws_size < total) return;

  bf16*  WQT = (bf16*)(ws + off_wqt);
  bf16*  WKT = (bf16*)(ws + off_wkt);
  bf16*  WVT = (bf16*)(ws + off_wvt);
  bf16*  WOT = (bf16*)(ws + off_wot);
  bf16*  KT  = (bf16*)(ws + off_kt);
  bf16*  Qb  = (bf16*)(ws + off_qb);
  bf16*  AV  = (bf16*)(ws + off_av);
  bf16*  VT  = (bf16*)(ws + off_vt);
  float* KVS = (float*)(ws + off_kvs);
  bf16*  BAV = (bf16*)(ws + off_bav);

  // prep
  k_prep_w4<<<dim3(32, 32, 4), 256, 0, stream>>>(Wq, Wk, Wv, Wo, WQT, WKT, WVT, WOT);
  k_init_vt<<<2048, 256, 0, stream>>>(VT);
  (void)hipMemsetAsync(KVS, 0, 1310720ull, stream);

  // fused cvt + all three projections in ONE dispatch (768 blocks, 2/CU)
  k_proj3<<<dim3(64, 4, 3), 512, 0, stream>>>(query, key, value,
                                              WQT, WKT, WVT,
                                              bq, bk, bvp,
                                              Qb, KT, VT);

  // state + normalizer
  k_kvs<<<dim3(16, 64), 256, 0, stream>>>(KT, VT, KVS);
  k_kvs_t<<<64, 256, 0, stream>>>(KVS, BAV);

  // attention readout + normalization
  k_av<<<dim3(32, 64), 256, 0, stream>>>(Qb, BAV, AV);

  // output projection
  k_gemm256<<<dim3(64, 4), 512, 0, stream>>>(AV, WOT, bo, out);
}

// Round 12
// 253.098 us; speedup vs baseline: 3.9714x; 3.9714x over previous
//
#include <hip/hip_runtime.h>
#include <stdint.h>

// ---------------------------------------------------------------------------
// Linear (kernelized) attention, B=4 L=4096 D=1024 H=16 M=64, fp32 in/out.
//   1. k_prep_w4: 4 weight transposes -> bf16 WT[out][in] (MFMA B layout)
//   2. k_projf  : FUSED fp32->bf16 + 256x256/BK=64 MFMA GEMM (2-barrier loop):
//                 A reg-staged from fp32 X (NT loads, cvt, swizzled ds_write;
//                 next tile's loads issued under compute = T14), B via
//                 gload16 w/ pre-swizzled source (T2).  LDS-transpose epilogue.
//                 MODE 0: q=relu(X Wq+b)+eps -> [B][L][1024]
//                 MODE 1: k -> kt [B][1024][L]   MODE 2: v -> vt [B][16][80][L]
//   3. k_gemm256: 8-phase GEMM, MODE 3 only: out = avn.WoT + bo (fp32)
//      k_init_vt: vt row 64 = 1.0 (kvs col 64 = ks_sum), 65..79 = 0
//   4. k_kvs    : per (b,h) kvs[64 m][80 d'] += kt . vt^T  (fp32 atomics)
//   5. k_kvs_t  : kvs fp32 -> bav bf16 [bh][80][64] (transpose)
//   6. k_av     : C[l][80] = q . bav^T; col 64 = norm; avn = C/norm (bf16)
// NOTE (round-11 lesson): 256^2 tile needs >=160 VGPR/wave; launch_bounds
// (512,4) forces 128 -> accumulator spill to scratch (GBs of traffic, 4x
// slower).  1 block/CU is structural for this tile geometry.
// ---------------------------------------------------------------------------

typedef __bf16 bf16;
typedef __bf16 bf16x4 __attribute__((ext_vector_type(4)));
typedef __bf16 bf16x8 __attribute__((ext_vector_type(8)));
typedef float f32x4 __attribute__((ext_vector_type(4)));

#define MFMA_(a, b, c) __builtin_amdgcn_mfma_f32_16x16x32_bf16((a), (b), (c), 0, 0, 0)

static constexpr int BB   = 4;
static constexpr int LSEQ = 4096;
static constexpr int DIM  = 1024;   // D == H*M
static constexpr int HH   = 16;
static constexpr float EPSF = 0.001f;

// ---- async global->LDS, 16B per lane, wave-uniform LDS base ---------------
__device__ __forceinline__ void gload16(bf16* lds, const bf16* g) {
  __builtin_amdgcn_global_load_lds(
      (const __attribute__((address_space(1))) void*)g,
      (__attribute__((address_space(3))) void*)lds, 16, 0, 0);
}

// ---------------- weight transpose: fp32 [1024][1024] -> bf16 out[c][r] ----
__global__ void k_prep_w4(const float* __restrict__ W0, const float* __restrict__ W1,
                          const float* __restrict__ W2, const float* __restrict__ W3,
                          bf16* __restrict__ T0, bf16* __restrict__ T1,
                          bf16* __restrict__ T2, bf16* __restrict__ T3) {
  const float* W; bf16* T;
  switch (blockIdx.z) {
    case 0:  W = W0; T = T0; break;
    case 1:  W = W1; T = T1; break;
    case 2:  W = W2; T = T2; break;
    default: W = W3; T = T3; break;
  }
  __shared__ float t[32][33];
  const int tx = threadIdx.x & 31, ty = threadIdx.x >> 5;   // 32 x 8
  const int r0 = blockIdx.x * 32, c0 = blockIdx.y * 32;
#pragma unroll
  for (int j = 0; j < 32; j += 8)
    t[ty + j][tx] = W[(size_t)(r0 + ty + j) * DIM + c0 + tx];
  __syncthreads();
#pragma unroll
  for (int j = 0; j < 32; j += 8)
    T[(size_t)(c0 + ty + j) * DIM + r0 + tx] = (bf16)t[tx][ty + j];
}

// ---------------- vt rows 64..79: row 64 = ones, rest zeros ----------------
__global__ void k_init_vt(bf16* __restrict__ vt) {
  const int c = blockIdx.x * 256 + threadIdx.x;
  const int l8 = c & 511;
  const int r  = (c >> 9) & 15;
  const int bh = c >> 13;
  const bf16 val = (r == 0) ? (bf16)1.0f : (bf16)0.0f;
  bf16x8 o;
#pragma unroll
  for (int j = 0; j < 8; ++j) o[j] = val;
  *reinterpret_cast<bf16x8*>(vt + ((size_t)bh * 80 + 64 + r) * LSEQ + l8 * 8) = o;
}

// ===========================================================================
// k_projf: fused cvt + projection GEMM.  256x256 tile, BK=64, 8 waves,
// single-buffered 2-barrier K-loop, 128 KiB LDS (1 block/CU).
// ===========================================================================
template <int MODE>
__global__ __launch_bounds__(512, 2) void k_projf(const float* __restrict__ X,
                                                  const bf16* __restrict__ WT,
                                                  const float* __restrict__ bias,
                                                  bf16* __restrict__ outp) {
  __shared__ __align__(16) bf16 SH[65536];      // 128 KiB (staging 64K + epi)
  bf16* As = SH;                                // 16384 elems: A tile 256x64
  bf16* Bs = SH + 16384;                        // 16384 elems: B tile 256x64
  const int tid = threadIdx.x;
  const int lane = tid & 63, w = tid >> 6;      // 8 waves
  const int wm = w >> 2, wn = w & 3;            // 2 x 4 wave grid
  const int lr = lane & 15, lk = (lane >> 4) & 3;
  const int n0 = blockIdx.x * 256, c0 = blockIdx.y * 256;
  const int swz = (lr & 7) * 8;
  const int col0 = (lk * 8) ^ swz;
  const int col1 = (lk * 8 + 32) ^ swz;
  const int srow = lane >> 3;
  const int scol = (((lane & 7) ^ ((lane >> 3) & 7)) * 8);
  const float* Xb = X + (size_t)n0 * DIM;
  const bf16* Bb = WT + (size_t)c0 * DIM;

  f32x4 acc[8][4] = {};
  f32x4 af[8];

  // prologue: A tile 0 -> regs
#pragma unroll
  for (int j = 0; j < 8; ++j) {
    const int idx = tid + j * 512, row = idx >> 4, c4 = idx & 15;
    af[j] = __builtin_nontemporal_load(
        reinterpret_cast<const f32x4*>(Xb + (size_t)row * DIM + c4 * 4));
  }

  for (int ks = 0; ks < 16; ++ks) {
    const int k0 = ks * 64;
    __syncthreads();                            // LDS free (prev reads done)
    // stage B tile ks (4 gload16 per wave)
#pragma unroll
    for (int rr = 0; rr < 4; ++rr) {
      const int row = (rr * 8 + w) * 8 + srow;
      gload16(Bs + (rr * 8 + w) * 512, Bb + (size_t)row * DIM + k0 + scol);
    }
    // write A tile ks from regs (fp32 -> bf16, swizzled)
#pragma unroll
    for (int j = 0; j < 8; ++j) {
      const int idx = tid + j * 512, row = idx >> 4, c4 = idx & 15;
      bf16x4 o;
      o[0] = (bf16)af[j][0]; o[1] = (bf16)af[j][1];
      o[2] = (bf16)af[j][2]; o[3] = (bf16)af[j][3];
      *reinterpret_cast<bf16x4*>(
          &As[row * 64 + ((((c4 >> 1) ^ (row & 7)) << 3) | ((c4 & 1) << 2))]) = o;
    }
    __syncthreads();                            // drains B vmcnt + A writes
    // issue next A tile's loads (fly under the MFMA block = T14)
    if (ks < 15) {
#pragma unroll
      for (int j = 0; j < 8; ++j) {
        const int idx = tid + j * 512, row = idx >> 4, c4 = idx & 15;
        af[j] = __builtin_nontemporal_load(
            reinterpret_cast<const f32x4*>(Xb + (size_t)row * DIM + k0 + 64 + c4 * 4));
      }
    }
    // compute: 64 MFMA
    bf16x8 a[8][2], b[4][2];
#pragma unroll
    for (int f = 0; f < 8; ++f) {
      a[f][0] = *reinterpret_cast<const bf16x8*>(&As[(wm * 128 + f * 16 + lr) * 64 + col0]);
      a[f][1] = *reinterpret_cast<const bf16x8*>(&As[(wm * 128 + f * 16 + lr) * 64 + col1]);
    }
#pragma unroll
    for (int cb = 0; cb < 4; ++cb) {
      b[cb][0] = *reinterpret_cast<const bf16x8*>(&Bs[(wn * 64 + cb * 16 + lr) * 64 + col0]);
      b[cb][1] = *reinterpret_cast<const bf16x8*>(&Bs[(wn * 64 + cb * 16 + lr) * 64 + col1]);
    }
#pragma unroll
    for (int kk = 0; kk < 2; ++kk)
#pragma unroll
      for (int f = 0; f < 8; ++f)
#pragma unroll
        for (int cb = 0; cb < 4; ++cb)
          acc[f][cb] = MFMA_(a[f][kk], b[cb][kk], acc[f][cb]);
  }

  // ---------------- epilogue (LDS-transpose, coalesced stores) --------------
  float bvv[4];
#pragma unroll
  for (int cb = 0; cb < 4; ++cb) bvv[cb] = bias[c0 + wn * 64 + cb * 16 + lr];
  const int bidx = n0 >> 12;
  const int l0 = n0 & (LSEQ - 1);

  if (MODE == 0) {
    __syncthreads();
#pragma unroll
    for (int f = 0; f < 8; ++f)
#pragma unroll
      for (int cb = 0; cb < 4; ++cb) {
        const int cl = wn * 64 + cb * 16 + lr;
#pragma unroll
        for (int r = 0; r < 4; ++r) {
          float x = acc[f][cb][r] + bvv[cb];
          x = fmaxf(x, 0.f) + EPSF;
          const int ll = wm * 128 + f * 16 + lk * 4 + r;
          SH[ll * 256 + ((((cl >> 3) ^ (ll & 7)) << 3) | (cl & 7))] = (bf16)x;
        }
      }
    __syncthreads();
#pragma unroll
    for (int it = 0; it < 16; ++it) {
      const int chunk = it * 512 + tid;
      const int row = chunk >> 5, blk = chunk & 31;
      const bf16x8 v = *reinterpret_cast<const bf16x8*>(&SH[row * 256 + ((blk ^ (row & 7)) << 3)]);
      *reinterpret_cast<bf16x8*>(outp + (size_t)(n0 + row) * DIM + c0 + blk * 8) = v;
    }
  } else {
    __syncthreads();
#pragma unroll
    for (int f = 0; f < 8; ++f)
#pragma unroll
      for (int cb = 0; cb < 4; ++cb) {
        const int cl = wn * 64 + cb * 16 + lr;
        const int ll = wm * 128 + f * 16 + lk * 4;
        bf16x4 o;
#pragma unroll
        for (int r = 0; r < 4; ++r) {
          float x = acc[f][cb][r] + bvv[cb];
          if (MODE == 1) x = fmaxf(x, 0.f) + EPSF;
          o[r] = (bf16)x;
        }
        *reinterpret_cast<bf16x4*>(
            &SH[cl * 256 + ((((ll >> 3) ^ (cl & 7)) << 3) | (ll & 7))]) = o;
      }
    __syncthreads();
#pragma unroll
    for (int it = 0; it < 16; ++it) {
      const int chunk = it * 512 + tid;
      const int row = chunk >> 5, blk = chunk & 31;   // row = local c
      const bf16x8 v = *reinterpret_cast<const bf16x8*>(&SH[row * 256 + ((blk ^ (row & 7)) << 3)]);
      const int cg = c0 + row;
      size_t rowbase;
      if (MODE == 1) rowbase = (size_t)bidx * 1024 + cg;                           // kt [b][c][L]
      else           rowbase = ((size_t)(bidx * HH + (cg >> 6)) * 80 + (cg & 63)); // vt [b][h][80][L]
      *reinterpret_cast<bf16x8*>(outp + rowbase * LSEQ + l0 + blk * 8) = v;
    }
  }
}

// ===========================================================================
// k_gemm256 (8-phase): out = A . WT^T + bias  (fp32)
// ===========================================================================
__device__ __forceinline__ void stage_half(bf16* As0, bf16* Bs0,
                                           const bf16* Ab, const bf16* Bb,
                                           int h, int w, int srow, int scol) {
  const int t = h >> 2, reg = h & 3, buf = t & 1;
  bf16* lds = ((reg < 2) ? As0 : Bs0) + buf * 16384 + (reg & 1) * 8192;
  const bf16* g = (reg < 2) ? Ab : Bb;
  const int rbase = (reg & 1) * 128;
#pragma unroll
  for (int rr = 0; rr < 2; ++rr) {
    const int row = rbase + (rr * 8 + w) * 8 + srow;
    gload16(lds + (rr * 8 + w) * 512, g + (size_t)row * DIM + t * 64 + scol);
  }
}

#define LDA(d, g, f)                                                                              \
  a[d][0] = *reinterpret_cast<const bf16x8*>(&As0[(g) * 16384 + (wm * 128 + (f) * 16 + lr) * 64 + col0]); \
  a[d][1] = *reinterpret_cast<const bf16x8*>(&As0[(g) * 16384 + (wm * 128 + (f) * 16 + lr) * 64 + col1]);
#define LDB(d, g, c)                                                                              \
  b[d][0] = *reinterpret_cast<const bf16x8*>(&Bs0[(g) * 16384 + (wn * 64 + (c) * 16 + lr) * 64 + col0]); \
  b[d][1] = *reinterpret_cast<const bf16x8*>(&Bs0[(g) * 16384 + (wn * 64 + (c) * 16 + lr) * 64 + col1]);
#define MM(fi, ci, fo, co)                                                                        \
  acc[fo][co] = MFMA_(a[fi][0], b[ci][0], acc[fo][co]);                                           \
  acc[fo][co] = MFMA_(a[fi][1], b[ci][1], acc[fo][co]);

#define PHASE(g, q, pidx)                                                                         \
  {                                                                                               \
    if ((q) == 0) { LDA(0, g, 0) LDA(1, g, 1) LDA(2, g, 2) LDA(3, g, 3)                           \
                    LDB(0, g, 0) LDB(1, g, 1) }                                                   \
    else if ((q) == 1) { LDB(0, g, 2) LDB(1, g, 3) }                                              \
    else if ((q) == 2) { LDA(0, g, 4) LDA(1, g, 5) LDA(2, g, 6) LDA(3, g, 7) }                    \
    else { LDB(0, g, 0) LDB(1, g, 1) }                                                            \
    const int hh = 8 * i + 5 + (pidx);                                                            \
    if (hh < 64) stage_half(As0, Bs0, Ab, Bb, hh, w, srow, scol);                                 \
    if ((pidx) == 3 || (pidx) == 7) {                                                             \
      if (i < 7) { asm volatile("s_waitcnt vmcnt(2)" ::: "memory"); }                             \
      else       { asm volatile("s_waitcnt vmcnt(0)" ::: "memory"); }                             \
    }                                                                                             \
    __builtin_amdgcn_sched_barrier(0);                                                            \
    __builtin_amdgcn_s_barrier();                                                                 \
    __builtin_amdgcn_sched_barrier(0);                                                            \
    __builtin_amdgcn_s_setprio(1);                                                                \
    if ((q) == 0) { MM(0, 0, 0, 0) MM(1, 0, 1, 0) MM(2, 0, 2, 0) MM(3, 0, 3, 0)                   \
                    MM(0, 1, 0, 1) MM(1, 1, 1, 1) MM(2, 1, 2, 1) MM(3, 1, 3, 1) }                 \
    else if ((q) == 1) { MM(0, 0, 0, 2) MM(1, 0, 1, 2) MM(2, 0, 2, 2) MM(3, 0, 3, 2)              \
                         MM(0, 1, 0, 3) MM(1, 1, 1, 3) MM(2, 1, 2, 3) MM(3, 1, 3, 3) }            \
    else if ((q) == 2) { MM(0, 0, 4, 2) MM(1, 0, 5, 2) MM(2, 0, 6, 2) MM(3, 0, 7, 2)              \
                         MM(0, 1, 4, 3) MM(1, 1, 5, 3) MM(2, 1, 6, 3) MM(3, 1, 7, 3) }            \
    else { MM(0, 0, 4, 0) MM(1, 0, 5, 0) MM(2, 0, 6, 0) MM(3, 0, 7, 0)                            \
           MM(0, 1, 4, 1) MM(1, 1, 5, 1) MM(2, 1, 6, 1) MM(3, 1, 7, 1) }                          \
    __builtin_amdgcn_s_setprio(0);                                                                \
    __builtin_amdgcn_sched_barrier(0);                                                            \
    __builtin_amdgcn_s_barrier();                                                                 \
    __builtin_amdgcn_sched_barrier(0);                                                            \
  }

__global__ __launch_bounds__(512, 2) void k_gemm256(const bf16* __restrict__ X,
                                                    const bf16* __restrict__ WT,
                                                    const float* __restrict__ bias,
                                                    float* __restrict__ outp) {
  __shared__ __align__(16) bf16 SH[65536];
  bf16* As0 = SH;
  bf16* Bs0 = SH + 32768;
  const int tid = threadIdx.x;
  const int lane = tid & 63, w = tid >> 6;
  const int wm = w >> 2, wn = w & 3;
  const int lr = lane & 15, lk = (lane >> 4) & 3;
  const int n0 = blockIdx.x * 256, c0 = blockIdx.y * 256;
  const int swz = (lr & 7) * 8;
  const int col0 = (lk * 8) ^ swz;
  const int col1 = (lk * 8 + 32) ^ swz;
  const int srow = lane >> 3;
  const int scol = (((lane & 7) ^ ((lane >> 3) & 7)) * 8);
  const bf16* Ab = X + (size_t)n0 * DIM;
  const bf16* Bb = WT + (size_t)c0 * DIM;

  f32x4 acc[8][4] = {};
  bf16x8 a[4][2], b[2][2];

#pragma unroll
  for (int h = 0; h < 5; ++h) stage_half(As0, Bs0, Ab, Bb, h, w, srow, scol);
  asm volatile("s_waitcnt vmcnt(2)" ::: "memory");
  __builtin_amdgcn_sched_barrier(0);
  __builtin_amdgcn_s_barrier();
  __builtin_amdgcn_sched_barrier(0);

  for (int i = 0; i < 8; ++i) {
    PHASE(0, 0, 0) PHASE(0, 1, 1) PHASE(0, 2, 2) PHASE(0, 3, 3)
    PHASE(1, 0, 4) PHASE(1, 1, 5) PHASE(1, 2, 6) PHASE(1, 3, 7)
  }

  float bvv[4];
#pragma unroll
  for (int cb = 0; cb < 4; ++cb) bvv[cb] = bias[c0 + wn * 64 + cb * 16 + lr];
#pragma unroll
  for (int f = 0; f < 8; ++f)
#pragma unroll
    for (int cb = 0; cb < 4; ++cb) {
      const int c = c0 + wn * 64 + cb * 16 + lr;
#pragma unroll
      for (int r = 0; r < 4; ++r) {
        const int row = n0 + wm * 128 + f * 16 + lk * 4 + r;
        outp[(size_t)row * DIM + c] = acc[f][cb][r] + bvv[cb];
      }
    }
}
#undef PHASE
#undef MM
#undef LDB
#undef LDA

// ---------------- kvs: per (b,h) C[64 m][80 d'] = kt . vt^T over l ---------
__global__ __launch_bounds__(256, 2) void k_kvs(const bf16* __restrict__ kt,
                                                const bf16* __restrict__ vt,
                                                float* __restrict__ kvs) {
  const int tid = threadIdx.x, lane = tid & 63, wid = tid >> 6;
  const int lr = lane & 15, lk = lane >> 4;
  const int bh = blockIdx.y;
  const int lbase = blockIdx.x * 256;       // 16 l-slices of 256
  __shared__ bf16 As[64][64];
  __shared__ bf16 Bs[80][64];
  f32x4 acc[5] = {};
  const bf16* ktb = kt + (size_t)bh * 64 * LSEQ;
  const bf16* vtb = vt + (size_t)bh * 80 * LSEQ;

  for (int ks = 0; ks < 4; ++ks) {
    const int l0 = lbase + ks * 64;
    __syncthreads();
#pragma unroll
    for (int i = 0; i < 2; ++i) {
      const int e = i * 2048 + tid * 8;
      const int row = e >> 6, col = e & 63;
      *reinterpret_cast<bf16x8*>(&As[row][col]) =
          *reinterpret_cast<const bf16x8*>(ktb + (size_t)row * LSEQ + l0 + col);
    }
#pragma unroll
    for (int i = 0; i < 2; ++i) {
      const int e = i * 2048 + tid * 8;
      const int row = e >> 6, col = e & 63;
      *reinterpret_cast<bf16x8*>(&Bs[row][col]) =
          *reinterpret_cast<const bf16x8*>(vtb + (size_t)row * LSEQ + l0 + col);
    }
    if (tid < 128) {
      const int e = 4096 + tid * 8;
      const int row = e >> 6, col = e & 63;
      *reinterpret_cast<bf16x8*>(&Bs[row][col]) =
          *reinterpret_cast<const bf16x8*>(vtb + (size_t)row * LSEQ + l0 + col);
    }
    __syncthreads();
#pragma unroll
    for (int kk = 0; kk < 2; ++kk) {
      const bf16x8 af = *reinterpret_cast<const bf16x8*>(&As[wid * 16 + lr][kk * 32 + lk * 8]);
#pragma unroll
      for (int cb = 0; cb < 5; ++cb) {
        const bf16x8 bfr = *reinterpret_cast<const bf16x8*>(&Bs[cb * 16 + lr][kk * 32 + lk * 8]);
        acc[cb] = MFMA_(af, bfr, acc[cb]);
      }
    }
  }
  float* kb = kvs + (size_t)bh * 64 * 80;
#pragma unroll
  for (int cb = 0; cb < 5; ++cb) {
    const int dcol = cb * 16 + lr;
#pragma unroll
    for (int r = 0; r < 4; ++r) {
      const int m = wid * 16 + lk * 4 + r;
      atomicAdd(kb + m * 80 + dcol, acc[cb][r]);
    }
  }
}

// ---------------- kvs fp32 [bh][64][80] -> bav bf16 [bh][80][64] -----------
__global__ void k_kvs_t(const float* __restrict__ kvs, bf16* __restrict__ bav) {
  const int bh = blockIdx.x;
  const float* src = kvs + (size_t)bh * 5120;
  bf16* dst = bav + (size_t)bh * 5120;
  for (int i = threadIdx.x; i < 5120; i += 256) {
    const int dp = i >> 6, mm = i & 63;
    dst[i] = (bf16)src[mm * 80 + dp];
  }
}

// ---------------- av: per (b,h) C[128 l][80] = q . bav^T; normalize --------
__global__ __launch_bounds__(256, 2) void k_av(const bf16* __restrict__ q,
                                               const bf16* __restrict__ bav,
                                               bf16* __restrict__ avn) {
  const int tid = threadIdx.x, lane = tid & 63, wid = tid >> 6;
  const int lr = lane & 15, lk = lane >> 4;
  const int bh = blockIdx.y, b = bh >> 4, h = bh & 15;
  const int l0 = blockIdx.x * 128;
  __shared__ bf16 As[128][64];
  __shared__ bf16 Bs[80][64];
  __shared__ float nrm[128];

  const bf16* qb = q + ((size_t)b * LSEQ + l0) * DIM + h * 64;
#pragma unroll
  for (int i = 0; i < 4; ++i) {
    const int e = i * 2048 + tid * 8;
    const int row = e >> 6, col = e & 63;
    *reinterpret_cast<bf16x8*>(&As[row][col]) =
        *reinterpret_cast<const bf16x8*>(qb + (size_t)row * DIM + col);
  }
  const bf16* bb = bav + (size_t)bh * 5120;
#pragma unroll
  for (int i = 0; i < 2; ++i) {
    const int e = i * 2048 + tid * 8;
    const int row = e >> 6, col = e & 63;
    *reinterpret_cast<bf16x8*>(&Bs[row][col]) =
        *reinterpret_cast<const bf16x8*>(bb + row * 64 + col);
  }
  if (tid < 128) {
    const int e = 4096 + tid * 8;
    const int row = e >> 6, col = e & 63;
    *reinterpret_cast<bf16x8*>(&Bs[row][col]) =
        *reinterpret_cast<const bf16x8*>(bb + row * 64 + col);
  }
  __syncthreads();

  f32x4 acc[2][5] = {};
#pragma unroll
  for (int kk = 0; kk < 2; ++kk) {
    bf16x8 af[2];
    af[0] = *reinterpret_cast<const bf16x8*>(&As[wid * 32 + lr][kk * 32 + lk * 8]);
    af[1] = *reinterpret_cast<const bf16x8*>(&As[wid * 32 + 16 + lr][kk * 32 + lk * 8]);
#pragma unroll
    for (int cb = 0; cb < 5; ++cb) {
      const bf16x8 bfr = *reinterpret_cast<const bf16x8*>(&Bs[cb * 16 + lr][kk * 32 + lk * 8]);
      acc[0][cb] = MFMA_(af[0], bfr, acc[0][cb]);
      acc[1][cb] = MFMA_(af[1], bfr, acc[1][cb]);
    }
  }
  if (lr == 0) {
#pragma unroll
    for (int rb = 0; rb < 2; ++rb)
#pragma unroll
      for (int r = 0; r < 4; ++r)
        nrm[wid * 32 + rb * 16 + lk * 4 + r] = acc[rb][4][r];
  }
  __syncthreads();
  bf16* ob = avn + ((size_t)b * LSEQ + l0) * DIM + h * 64;
#pragma unroll
  for (int rb = 0; rb < 2; ++rb) {
#pragma unroll
    for (int cb = 0; cb < 4; ++cb) {
#pragma unroll
      for (int r = 0; r < 4; ++r) {
        const int row = wid * 32 + rb * 16 + lk * 4 + r;
        const float x = acc[rb][cb][r] / nrm[row];
        ob[(size_t)row * DIM + cb * 16 + lr] = (bf16)x;
      }
    }
  }
}

// ---------------------------------------------------------------------------
extern "C" void kernel_launch(void* const* d_in, const int* in_sizes, int n_in,
                              void* d_out, int out_size, void* d_ws, size_t ws_size,
                              hipStream_t stream) {
  const float* query = (const float*)d_in[0];
  const float* key   = (const float*)d_in[1];
  const float* value = (const float*)d_in[2];
  const float* Wq    = (const float*)d_in[3];
  const float* bq    = (const float*)d_in[4];
  const float* Wk    = (const float*)d_in[5];
  const float* bk    = (const float*)d_in[6];
  const float* Wv    = (const float*)d_in[7];
  const float* bvp   = (const float*)d_in[8];
  const float* Wo    = (const float*)d_in[9];
  const float* bo    = (const float*)d_in[10];
  float* out = (float*)d_out;
  char* ws = (char*)d_ws;

  const size_t off_wqt = 0;                        // 2 MB each
  const size_t off_wkt = off_wqt + (2u << 20);
  const size_t off_wvt = off_wkt + (2u << 20);
  const size_t off_wot = off_wvt + (2u << 20);
  const size_t off_kt  = off_wot + (2u << 20);     // 33,554,432
  const size_t off_qb  = off_kt  + 33554432ull;    // 33,554,432
  const size_t off_av  = off_qb  + 33554432ull;    // 33,554,432
  const size_t off_vt  = off_av  + 33554432ull;    // 41,943,040
  const size_t off_kvs = off_vt  + 41943040ull;    //  1,310,720 (fp32)
  const size_t off_bav = off_kvs + 1310720ull;     //    655,360
  const size_t total   = off_bav + 655360ull;      // ~146 MB
  if (ws_size < total) return;

  bf16*  WQT = (bf16*)(ws + off_wqt);
  bf16*  WKT = (bf16*)(ws + off_wkt);
  bf16*  WVT = (bf16*)(ws + off_wvt);
  bf16*  WOT = (bf16*)(ws + off_wot);
  bf16*  KT  = (bf16*)(ws + off_kt);
  bf16*  Qb  = (bf16*)(ws + off_qb);
  bf16*  AV  = (bf16*)(ws + off_av);
  bf16*  VT  = (bf16*)(ws + off_vt);
  float* KVS = (float*)(ws + off_kvs);
  bf16*  BAV = (bf16*)(ws + off_bav);

  // prep
  k_prep_w4<<<dim3(32, 32, 4), 256, 0, stream>>>(Wq, Wk, Wv, Wo, WQT, WKT, WVT, WOT);
  k_init_vt<<<2048, 256, 0, stream>>>(VT);
  (void)hipMemsetAsync(KVS, 0, 1310720ull, stream);

  // fused cvt+projections
  k_projf<2><<<dim3(64, 4), 512, 0, stream>>>(value, WVT, bvp, VT);
  k_projf<1><<<dim3(64, 4), 512, 0, stream>>>(key,   WKT, bk, KT);
  k_projf<0><<<dim3(64, 4), 512, 0, stream>>>(query, WQT, bq, Qb);

  // state + normalizer
  k_kvs<<<dim3(16, 64), 256, 0, stream>>>(KT, VT, KVS);
  k_kvs_t<<<64, 256, 0, stream>>>(KVS, BAV);

  // attention readout + normalization
  k_av<<<dim3(32, 64), 256, 0, stream>>>(Qb, BAV, AV);

  // output projection
  k_gemm256<<<dim3(64, 4), 512, 0, stream>>>(AV, WOT, bo, out);
}

// Round 13
// 248.401 us; speedup vs baseline: 4.0465x; 1.0189x over previous
//
#include <hip/hip_runtime.h>
#include <stdint.h>

// ---------------------------------------------------------------------------
// Linear (kernelized) attention, B=4 L=4096 D=1024 H=16 M=64, fp32 in/out.
//   1. k_prep_w4: 4 weight transposes -> bf16 WT[out][in] (MFMA B layout)
//   2. k_projf3 : ONE z-grid dispatch (64,4,3) = {v,k,q}.  FUSED fp32->bf16 +
//                 256x256/BK=64 MFMA GEMM (2-barrier loop): A reg-staged from
//                 fp32 X (NT loads, cvt, swizzled ds_write; next tile's loads
//                 issued under compute = T14), B via gload16 w/ pre-swizzled
//                 source (T2).  128 KiB LDS, launch_bounds(512,2) -- do NOT
//                 raise the occupancy bound (round-11: (512,4) caps VGPR at
//                 128 -> accumulator spill -> 4x slower).
//                 z=2: q=relu(X Wq+b)+eps -> [B][L][1024]
//                 z=1: k -> kt [B][1024][L]   z=0: v -> vt [B][16][80][L]
//   3. k_gemm256: 8-phase GEMM: out = avn.WoT + bo (fp32)
//      k_init_vt: vt row 64 = 1.0 (kvs col 64 = ks_sum), 65..79 = 0
//   4. k_kvs    : per (b,h) kvs[64 m][80 d'] += kt . vt^T  (fp32 atomics)
//   5. k_kvs_t  : kvs fp32 -> bav bf16 [bh][80][64] (transpose)
//   6. k_av     : C[l][80] = q . bav^T; col 64 = norm; avn = C/norm (bf16)
// ---------------------------------------------------------------------------

typedef __bf16 bf16;
typedef __bf16 bf16x4 __attribute__((ext_vector_type(4)));
typedef __bf16 bf16x8 __attribute__((ext_vector_type(8)));
typedef float f32x4 __attribute__((ext_vector_type(4)));

#define MFMA_(a, b, c) __builtin_amdgcn_mfma_f32_16x16x32_bf16((a), (b), (c), 0, 0, 0)

static constexpr int BB   = 4;
static constexpr int LSEQ = 4096;
static constexpr int DIM  = 1024;   // D == H*M
static constexpr int HH   = 16;
static constexpr float EPSF = 0.001f;

// ---- async global->LDS, 16B per lane, wave-uniform LDS base ---------------
__device__ __forceinline__ void gload16(bf16* lds, const bf16* g) {
  __builtin_amdgcn_global_load_lds(
      (const __attribute__((address_space(1))) void*)g,
      (__attribute__((address_space(3))) void*)lds, 16, 0, 0);
}

// ---------------- weight transpose: fp32 [1024][1024] -> bf16 out[c][r] ----
__global__ void k_prep_w4(const float* __restrict__ W0, const float* __restrict__ W1,
                          const float* __restrict__ W2, const float* __restrict__ W3,
                          bf16* __restrict__ T0, bf16* __restrict__ T1,
                          bf16* __restrict__ T2, bf16* __restrict__ T3) {
  const float* W; bf16* T;
  switch (blockIdx.z) {
    case 0:  W = W0; T = T0; break;
    case 1:  W = W1; T = T1; break;
    case 2:  W = W2; T = T2; break;
    default: W = W3; T = T3; break;
  }
  __shared__ float t[32][33];
  const int tx = threadIdx.x & 31, ty = threadIdx.x >> 5;   // 32 x 8
  const int r0 = blockIdx.x * 32, c0 = blockIdx.y * 32;
#pragma unroll
  for (int j = 0; j < 32; j += 8)
    t[ty + j][tx] = W[(size_t)(r0 + ty + j) * DIM + c0 + tx];
  __syncthreads();
#pragma unroll
  for (int j = 0; j < 32; j += 8)
    T[(size_t)(c0 + ty + j) * DIM + r0 + tx] = (bf16)t[tx][ty + j];
}

// ---------------- vt rows 64..79: row 64 = ones, rest zeros ----------------
__global__ void k_init_vt(bf16* __restrict__ vt) {
  const int c = blockIdx.x * 256 + threadIdx.x;
  const int l8 = c & 511;
  const int r  = (c >> 9) & 15;
  const int bh = c >> 13;
  const bf16 val = (r == 0) ? (bf16)1.0f : (bf16)0.0f;
  bf16x8 o;
#pragma unroll
  for (int j = 0; j < 8; ++j) o[j] = val;
  *reinterpret_cast<bf16x8*>(vt + ((size_t)bh * 80 + 64 + r) * LSEQ + l8 * 8) = o;
}

// ===========================================================================
// k_projf3: fused cvt + projection GEMM, all three projections in one
// z-grid dispatch.  256x256 tile, BK=64, 8 waves, single-buffered 2-barrier
// K-loop, 128 KiB LDS (1 block/CU).
// ===========================================================================
__global__ __launch_bounds__(512, 2) void k_projf3(
    const float* __restrict__ Xq, const float* __restrict__ Xk, const float* __restrict__ Xv,
    const bf16* __restrict__ WQT, const bf16* __restrict__ WKT, const bf16* __restrict__ WVT,
    const float* __restrict__ bq, const float* __restrict__ bk, const float* __restrict__ bv,
    bf16* __restrict__ Qb, bf16* __restrict__ KT, bf16* __restrict__ VT) {
  __shared__ __align__(16) bf16 SH[65536];      // 128 KiB (staging 64K + epi)
  bf16* As = SH;                                // 16384 elems: A tile 256x64
  bf16* Bs = SH + 16384;                        // 16384 elems: B tile 256x64
  const int mode = 2 - (int)blockIdx.z;         // z=0 -> v(2), z=1 -> k(1), z=2 -> q(0)
  const float* X    = (mode == 0) ? Xq  : (mode == 1) ? Xk  : Xv;
  const bf16*  WT   = (mode == 0) ? WQT : (mode == 1) ? WKT : WVT;
  const float* bias = (mode == 0) ? bq  : (mode == 1) ? bk  : bv;
  bf16*        outp = (mode == 0) ? Qb  : (mode == 1) ? KT  : VT;

  const int tid = threadIdx.x;
  const int lane = tid & 63, w = tid >> 6;      // 8 waves
  const int wm = w >> 2, wn = w & 3;            // 2 x 4 wave grid
  const int lr = lane & 15, lk = (lane >> 4) & 3;
  const int n0 = blockIdx.x * 256, c0 = blockIdx.y * 256;
  const int swz = (lr & 7) * 8;
  const int col0 = (lk * 8) ^ swz;
  const int col1 = (lk * 8 + 32) ^ swz;
  const int srow = lane >> 3;
  const int scol = (((lane & 7) ^ ((lane >> 3) & 7)) * 8);
  const float* Xb = X + (size_t)n0 * DIM;
  const bf16* Bb = WT + (size_t)c0 * DIM;

  f32x4 acc[8][4] = {};
  f32x4 af[8];

  // prologue: A tile 0 -> regs
#pragma unroll
  for (int j = 0; j < 8; ++j) {
    const int idx = tid + j * 512, row = idx >> 4, c4 = idx & 15;
    af[j] = __builtin_nontemporal_load(
        reinterpret_cast<const f32x4*>(Xb + (size_t)row * DIM + c4 * 4));
  }

  for (int ks = 0; ks < 16; ++ks) {
    const int k0 = ks * 64;
    __syncthreads();                            // LDS free (prev reads done)
    // stage B tile ks (4 gload16 per wave)
#pragma unroll
    for (int rr = 0; rr < 4; ++rr) {
      const int row = (rr * 8 + w) * 8 + srow;
      gload16(Bs + (rr * 8 + w) * 512, Bb + (size_t)row * DIM + k0 + scol);
    }
    // write A tile ks from regs (fp32 -> bf16, swizzled)
#pragma unroll
    for (int j = 0; j < 8; ++j) {
      const int idx = tid + j * 512, row = idx >> 4, c4 = idx & 15;
      bf16x4 o;
      o[0] = (bf16)af[j][0]; o[1] = (bf16)af[j][1];
      o[2] = (bf16)af[j][2]; o[3] = (bf16)af[j][3];
      *reinterpret_cast<bf16x4*>(
          &As[row * 64 + ((((c4 >> 1) ^ (row & 7)) << 3) | ((c4 & 1) << 2))]) = o;
    }
    __syncthreads();                            // drains B vmcnt + A writes
    // issue next A tile's loads (fly under the MFMA block = T14)
    if (ks < 15) {
#pragma unroll
      for (int j = 0; j < 8; ++j) {
        const int idx = tid + j * 512, row = idx >> 4, c4 = idx & 15;
        af[j] = __builtin_nontemporal_load(
            reinterpret_cast<const f32x4*>(Xb + (size_t)row * DIM + k0 + 64 + c4 * 4));
      }
    }
    // compute: 64 MFMA
    bf16x8 a[8][2], b[4][2];
#pragma unroll
    for (int f = 0; f < 8; ++f) {
      a[f][0] = *reinterpret_cast<const bf16x8*>(&As[(wm * 128 + f * 16 + lr) * 64 + col0]);
      a[f][1] = *reinterpret_cast<const bf16x8*>(&As[(wm * 128 + f * 16 + lr) * 64 + col1]);
    }
#pragma unroll
    for (int cb = 0; cb < 4; ++cb) {
      b[cb][0] = *reinterpret_cast<const bf16x8*>(&Bs[(wn * 64 + cb * 16 + lr) * 64 + col0]);
      b[cb][1] = *reinterpret_cast<const bf16x8*>(&Bs[(wn * 64 + cb * 16 + lr) * 64 + col1]);
    }
#pragma unroll
    for (int kk = 0; kk < 2; ++kk)
#pragma unroll
      for (int f = 0; f < 8; ++f)
#pragma unroll
        for (int cb = 0; cb < 4; ++cb)
          acc[f][cb] = MFMA_(a[f][kk], b[cb][kk], acc[f][cb]);
  }

  // ---------------- epilogue (LDS-transpose, coalesced stores) --------------
  float bvv[4];
#pragma unroll
  for (int cb = 0; cb < 4; ++cb) bvv[cb] = bias[c0 + wn * 64 + cb * 16 + lr];
  const int bidx = n0 >> 12;
  const int l0 = n0 & (LSEQ - 1);

  if (mode == 0) {
    __syncthreads();
#pragma unroll
    for (int f = 0; f < 8; ++f)
#pragma unroll
      for (int cb = 0; cb < 4; ++cb) {
        const int cl = wn * 64 + cb * 16 + lr;
#pragma unroll
        for (int r = 0; r < 4; ++r) {
          float x = acc[f][cb][r] + bvv[cb];
          x = fmaxf(x, 0.f) + EPSF;
          const int ll = wm * 128 + f * 16 + lk * 4 + r;
          SH[ll * 256 + ((((cl >> 3) ^ (ll & 7)) << 3) | (cl & 7))] = (bf16)x;
        }
      }
    __syncthreads();
#pragma unroll
    for (int it = 0; it < 16; ++it) {
      const int chunk = it * 512 + tid;
      const int row = chunk >> 5, blk = chunk & 31;
      const bf16x8 v = *reinterpret_cast<const bf16x8*>(&SH[row * 256 + ((blk ^ (row & 7)) << 3)]);
      *reinterpret_cast<bf16x8*>(outp + (size_t)(n0 + row) * DIM + c0 + blk * 8) = v;
    }
  } else {
    __syncthreads();
#pragma unroll
    for (int f = 0; f < 8; ++f)
#pragma unroll
      for (int cb = 0; cb < 4; ++cb) {
        const int cl = wn * 64 + cb * 16 + lr;
        const int ll = wm * 128 + f * 16 + lk * 4;
        bf16x4 o;
#pragma unroll
        for (int r = 0; r < 4; ++r) {
          float x = acc[f][cb][r] + bvv[cb];
          if (mode == 1) x = fmaxf(x, 0.f) + EPSF;
          o[r] = (bf16)x;
        }
        *reinterpret_cast<bf16x4*>(
            &SH[cl * 256 + ((((ll >> 3) ^ (cl & 7)) << 3) | (ll & 7))]) = o;
      }
    __syncthreads();
#pragma unroll
    for (int it = 0; it < 16; ++it) {
      const int chunk = it * 512 + tid;
      const int row = chunk >> 5, blk = chunk & 31;   // row = local c
      const bf16x8 v = *reinterpret_cast<const bf16x8*>(&SH[row * 256 + ((blk ^ (row & 7)) << 3)]);
      const int cg = c0 + row;
      size_t rowbase;
      if (mode == 1) rowbase = (size_t)bidx * 1024 + cg;                           // kt [b][c][L]
      else           rowbase = ((size_t)(bidx * HH + (cg >> 6)) * 80 + (cg & 63)); // vt [b][h][80][L]
      *reinterpret_cast<bf16x8*>(outp + rowbase * LSEQ + l0 + blk * 8) = v;
    }
  }
}

// ===========================================================================
// k_gemm256 (8-phase): out = A . WT^T + bias  (fp32)
// ===========================================================================
__device__ __forceinline__ void stage_half(bf16* As0, bf16* Bs0,
                                           const bf16* Ab, const bf16* Bb,
                                           int h, int w, int srow, int scol) {
  const int t = h >> 2, reg = h & 3, buf = t & 1;
  bf16* lds = ((reg < 2) ? As0 : Bs0) + buf * 16384 + (reg & 1) * 8192;
  const bf16* g = (reg < 2) ? Ab : Bb;
  const int rbase = (reg & 1) * 128;
#pragma unroll
  for (int rr = 0; rr < 2; ++rr) {
    const int row = rbase + (rr * 8 + w) * 8 + srow;
    gload16(lds + (rr * 8 + w) * 512, g + (size_t)row * DIM + t * 64 + scol);
  }
}

#define LDA(d, g, f)                                                                              \
  a[d][0] = *reinterpret_cast<const bf16x8*>(&As0[(g) * 16384 + (wm * 128 + (f) * 16 + lr) * 64 + col0]); \
  a[d][1] = *reinterpret_cast<const bf16x8*>(&As0[(g) * 16384 + (wm * 128 + (f) * 16 + lr) * 64 + col1]);
#define LDB(d, g, c)                                                                              \
  b[d][0] = *reinterpret_cast<const bf16x8*>(&Bs0[(g) * 16384 + (wn * 64 + (c) * 16 + lr) * 64 + col0]); \
  b[d][1] = *reinterpret_cast<const bf16x8*>(&Bs0[(g) * 16384 + (wn * 64 + (c) * 16 + lr) * 64 + col1]);
#define MM(fi, ci, fo, co)                                                                        \
  acc[fo][co] = MFMA_(a[fi][0], b[ci][0], acc[fo][co]);                                           \
  acc[fo][co] = MFMA_(a[fi][1], b[ci][1], acc[fo][co]);

#define PHASE(g, q, pidx)                                                                         \
  {                                                                                               \
    if ((q) == 0) { LDA(0, g, 0) LDA(1, g, 1) LDA(2, g, 2) LDA(3, g, 3)                           \
                    LDB(0, g, 0) LDB(1, g, 1) }                                                   \
    else if ((q) == 1) { LDB(0, g, 2) LDB(1, g, 3) }                                              \
    else if ((q) == 2) { LDA(0, g, 4) LDA(1, g, 5) LDA(2, g, 6) LDA(3, g, 7) }                    \
    else { LDB(0, g, 0) LDB(1, g, 1) }                                                            \
    const int hh = 8 * i + 5 + (pidx);                                                            \
    if (hh < 64) stage_half(As0, Bs0, Ab, Bb, hh, w, srow, scol);                                 \
    if ((pidx) == 3 || (pidx) == 7) {                                                             \
      if (i < 7) { asm volatile("s_waitcnt vmcnt(2)" ::: "memory"); }                             \
      else       { asm volatile("s_waitcnt vmcnt(0)" ::: "memory"); }                             \
    }                                                                                             \
    __builtin_amdgcn_sched_barrier(0);                                                            \
    __builtin_amdgcn_s_barrier();                                                                 \
    __builtin_amdgcn_sched_barrier(0);                                                            \
    __builtin_amdgcn_s_setprio(1);                                                                \
    if ((q) == 0) { MM(0, 0, 0, 0) MM(1, 0, 1, 0) MM(2, 0, 2, 0) MM(3, 0, 3, 0)                   \
                    MM(0, 1, 0, 1) MM(1, 1, 1, 1) MM(2, 1, 2, 1) MM(3, 1, 3, 1) }                 \
    else if ((q) == 1) { MM(0, 0, 0, 2) MM(1, 0, 1, 2) MM(2, 0, 2, 2) MM(3, 0, 3, 2)              \
                         MM(0, 1, 0, 3) MM(1, 1, 1, 3) MM(2, 1, 2, 3) MM(3, 1, 3, 3) }            \
    else if ((q) == 2) { MM(0, 0, 4, 2) MM(1, 0, 5, 2) MM(2, 0, 6, 2) MM(3, 0, 7, 2)              \
                         MM(0, 1, 4, 3) MM(1, 1, 5, 3) MM(2, 1, 6, 3) MM(3, 1, 7, 3) }            \
    else { MM(0, 0, 4, 0) MM(1, 0, 5, 0) MM(2, 0, 6, 0) MM(3, 0, 7, 0)                            \
           MM(0, 1, 4, 1) MM(1, 1, 5, 1) MM(2, 1, 6, 1) MM(3, 1, 7, 1) }                          \
    __builtin_amdgcn_s_setprio(0);                                                                \
    __builtin_amdgcn_sched_barrier(0);                                                            \
    __builtin_amdgcn_s_barrier();                                                                 \
    __builtin_amdgcn_sched_barrier(0);                                                            \
  }

__global__ __launch_bounds__(512, 2) void k_gemm256(const bf16* __restrict__ X,
                                                    const bf16* __restrict__ WT,
                                                    const float* __restrict__ bias,
                                                    float* __restrict__ outp) {
  __shared__ __align__(16) bf16 SH[65536];
  bf16* As0 = SH;
  bf16* Bs0 = SH + 32768;
  const int tid = threadIdx.x;
  const int lane = tid & 63, w = tid >> 6;
  const int wm = w >> 2, wn = w & 3;
  const int lr = lane & 15, lk = (lane >> 4) & 3;
  const int n0 = blockIdx.x * 256, c0 = blockIdx.y * 256;
  const int swz = (lr & 7) * 8;
  const int col0 = (lk * 8) ^ swz;
  const int col1 = (lk * 8 + 32) ^ swz;
  const int srow = lane >> 3;
  const int scol = (((lane & 7) ^ ((lane >> 3) & 7)) * 8);
  const bf16* Ab = X + (size_t)n0 * DIM;
  const bf16* Bb = WT + (size_t)c0 * DIM;

  f32x4 acc[8][4] = {};
  bf16x8 a[4][2], b[2][2];

#pragma unroll
  for (int h = 0; h < 5; ++h) stage_half(As0, Bs0, Ab, Bb, h, w, srow, scol);
  asm volatile("s_waitcnt vmcnt(2)" ::: "memory");
  __builtin_amdgcn_sched_barrier(0);
  __builtin_amdgcn_s_barrier();
  __builtin_amdgcn_sched_barrier(0);

  for (int i = 0; i < 8; ++i) {
    PHASE(0, 0, 0) PHASE(0, 1, 1) PHASE(0, 2, 2) PHASE(0, 3, 3)
    PHASE(1, 0, 4) PHASE(1, 1, 5) PHASE(1, 2, 6) PHASE(1, 3, 7)
  }

  float bvv[4];
#pragma unroll
  for (int cb = 0; cb < 4; ++cb) bvv[cb] = bias[c0 + wn * 64 + cb * 16 + lr];
#pragma unroll
  for (int f = 0; f < 8; ++f)
#pragma unroll
    for (int cb = 0; cb < 4; ++cb) {
      const int c = c0 + wn * 64 + cb * 16 + lr;
#pragma unroll
      for (int r = 0; r < 4; ++r) {
        const int row = n0 + wm * 128 + f * 16 + lk * 4 + r;
        outp[(size_t)row * DIM + c] = acc[f][cb][r] + bvv[cb];
      }
    }
}
#undef PHASE
#undef MM
#undef LDB
#undef LDA

// ---------------- kvs: per (b,h) C[64 m][80 d'] = kt . vt^T over l ---------
__global__ __launch_bounds__(256, 2) void k_kvs(const bf16* __restrict__ kt,
                                                const bf16* __restrict__ vt,
                                                float* __restrict__ kvs) {
  const int tid = threadIdx.x, lane = tid & 63, wid = tid >> 6;
  const int lr = lane & 15, lk = lane >> 4;
  const int bh = blockIdx.y;
  const int lbase = blockIdx.x * 256;       // 16 l-slices of 256
  __shared__ bf16 As[64][64];
  __shared__ bf16 Bs[80][64];
  f32x4 acc[5] = {};
  const bf16* ktb = kt + (size_t)bh * 64 * LSEQ;
  const bf16* vtb = vt + (size_t)bh * 80 * LSEQ;

  for (int ks = 0; ks < 4; ++ks) {
    const int l0 = lbase + ks * 64;
    __syncthreads();
#pragma unroll
    for (int i = 0; i < 2; ++i) {
      const int e = i * 2048 + tid * 8;
      const int row = e >> 6, col = e & 63;
      *reinterpret_cast<bf16x8*>(&As[row][col]) =
          *reinterpret_cast<const bf16x8*>(ktb + (size_t)row * LSEQ + l0 + col);
    }
#pragma unroll
    for (int i = 0; i < 2; ++i) {
      const int e = i * 2048 + tid * 8;
      const int row = e >> 6, col = e & 63;
      *reinterpret_cast<bf16x8*>(&Bs[row][col]) =
          *reinterpret_cast<const bf16x8*>(vtb + (size_t)row * LSEQ + l0 + col);
    }
    if (tid < 128) {
      const int e = 4096 + tid * 8;
      const int row = e >> 6, col = e & 63;
      *reinterpret_cast<bf16x8*>(&Bs[row][col]) =
          *reinterpret_cast<const bf16x8*>(vtb + (size_t)row * LSEQ + l0 + col);
    }
    __syncthreads();
#pragma unroll
    for (int kk = 0; kk < 2; ++kk) {
      const bf16x8 af = *reinterpret_cast<const bf16x8*>(&As[wid * 16 + lr][kk * 32 + lk * 8]);
#pragma unroll
      for (int cb = 0; cb < 5; ++cb) {
        const bf16x8 bfr = *reinterpret_cast<const bf16x8*>(&Bs[cb * 16 + lr][kk * 32 + lk * 8]);
        acc[cb] = MFMA_(af, bfr, acc[cb]);
      }
    }
  }
  float* kb = kvs + (size_t)bh * 64 * 80;
#pragma unroll
  for (int cb = 0; cb < 5; ++cb) {
    const int dcol = cb * 16 + lr;
#pragma unroll
    for (int r = 0; r < 4; ++r) {
      const int m = wid * 16 + lk * 4 + r;
      atomicAdd(kb + m * 80 + dcol, acc[cb][r]);
    }
  }
}

// ---------------- kvs fp32 [bh][64][80] -> bav bf16 [bh][80][64] -----------
__global__ void k_kvs_t(const float* __restrict__ kvs, bf16* __restrict__ bav) {
  const int bh = blockIdx.x;
  const float* src = kvs + (size_t)bh * 5120;
  bf16* dst = bav + (size_t)bh * 5120;
  for (int i = threadIdx.x; i < 5120; i += 256) {
    const int dp = i >> 6, mm = i & 63;
    dst[i] = (bf16)src[mm * 80 + dp];
  }
}

// ---------------- av: per (b,h) C[128 l][80] = q . bav^T; normalize --------
__global__ __launch_bounds__(256, 2) void k_av(const bf16* __restrict__ q,
                                               const bf16* __restrict__ bav,
                                               bf16* __restrict__ avn) {
  const int tid = threadIdx.x, lane = tid & 63, wid = tid >> 6;
  const int lr = lane & 15, lk = lane >> 4;
  const int bh = blockIdx.y, b = bh >> 4, h = bh & 15;
  const int l0 = blockIdx.x * 128;
  __shared__ bf16 As[128][64];
  __shared__ bf16 Bs[80][64];
  __shared__ float nrm[128];

  const bf16* qb = q + ((size_t)b * LSEQ + l0) * DIM + h * 64;
#pragma unroll
  for (int i = 0; i < 4; ++i) {
    const int e = i * 2048 + tid * 8;
    const int row = e >> 6, col = e & 63;
    *reinterpret_cast<bf16x8*>(&As[row][col]) =
        *reinterpret_cast<const bf16x8*>(qb + (size_t)row * DIM + col);
  }
  const bf16* bb = bav + (size_t)bh * 5120;
#pragma unroll
  for (int i = 0; i < 2; ++i) {
    const int e = i * 2048 + tid * 8;
    const int row = e >> 6, col = e & 63;
    *reinterpret_cast<bf16x8*>(&Bs[row][col]) =
        *reinterpret_cast<const bf16x8*>(bb + row * 64 + col);
  }
  if (tid < 128) {
    const int e = 4096 + tid * 8;
    const int row = e >> 6, col = e & 63;
    *reinterpret_cast<bf16x8*>(&Bs[row][col]) =
        *reinterpret_cast<const bf16x8*>(bb + row * 64 + col);
  }
  __syncthreads();

  f32x4 acc[2][5] = {};
#pragma unroll
  for (int kk = 0; kk < 2; ++kk) {
    bf16x8 af[2];
    af[0] = *reinterpret_cast<const bf16x8*>(&As[wid * 32 + lr][kk * 32 + lk * 8]);
    af[1] = *reinterpret_cast<const bf16x8*>(&As[wid * 32 + 16 + lr][kk * 32 + lk * 8]);
#pragma unroll
    for (int cb = 0; cb < 5; ++cb) {
      const bf16x8 bfr = *reinterpret_cast<const bf16x8*>(&Bs[cb * 16 + lr][kk * 32 + lk * 8]);
      acc[0][cb] = MFMA_(af[0], bfr, acc[0][cb]);
      acc[1][cb] = MFMA_(af[1], bfr, acc[1][cb]);
    }
  }
  if (lr == 0) {
#pragma unroll
    for (int rb = 0; rb < 2; ++rb)
#pragma unroll
      for (int r = 0; r < 4; ++r)
        nrm[wid * 32 + rb * 16 + lk * 4 + r] = acc[rb][4][r];
  }
  __syncthreads();
  bf16* ob = avn + ((size_t)b * LSEQ + l0) * DIM + h * 64;
#pragma unroll
  for (int rb = 0; rb < 2; ++rb) {
#pragma unroll
    for (int cb = 0; cb < 4; ++cb) {
#pragma unroll
      for (int r = 0; r < 4; ++r) {
        const int row = wid * 32 + rb * 16 + lk * 4 + r;
        const float x = acc[rb][cb][r] / nrm[row];
        ob[(size_t)row * DIM + cb * 16 + lr] = (bf16)x;
      }
    }
  }
}

// ---------------------------------------------------------------------------
extern "C" void kernel_launch(void* const* d_in, const int* in_sizes, int n_in,
                              void* d_out, int out_size, void* d_ws, size_t ws_size,
                              hipStream_t stream) {
  const float* query = (const float*)d_in[0];
  const float* key   = (const float*)d_in[1];
  const float* value = (const float*)d_in[2];
  const float* Wq    = (const float*)d_in[3];
  const float* bq    = (const float*)d_in[4];
  const float* Wk    = (const float*)d_in[5];
  const float* bk    = (const float*)d_in[6];
  const float* Wv    = (const float*)d_in[7];
  const float* bvp   = (const float*)d_in[8];
  const float* Wo    = (const float*)d_in[9];
  const float* bo    = (const float*)d_in[10];
  float* out = (float*)d_out;
  char* ws = (char*)d_ws;

  const size_t off_wqt = 0;                        // 2 MB each
  const size_t off_wkt = off_wqt + (2u << 20);
  const size_t off_wvt = off_wkt + (2u << 20);
  const size_t off_wot = off_wvt + (2u << 20);
  const size_t off_kt  = off_wot + (2u << 20);     // 33,554,432
  const size_t off_qb  = off_kt  + 33554432ull;    // 33,554,432
  const size_t off_av  = off_qb  + 33554432ull;    // 33,554,432
  const size_t off_vt  = off_av  + 33554432ull;    // 41,943,040
  const size_t off_kvs = off_vt  + 41943040ull;    //  1,310,720 (fp32)
  const size_t off_bav = off_kvs + 1310720ull;     //    655,360
  const size_t total   = off_bav + 655360ull;      // ~146 MB
  if (ws_size < total) return;

  bf16*  WQT = (bf16*)(ws + off_wqt);
  bf16*  WKT = (bf16*)(ws + off_wkt);
  bf16*  WVT = (bf16*)(ws + off_wvt);
  bf16*  WOT = (bf16*)(ws + off_wot);
  bf16*  KT  = (bf16*)(ws + off_kt);
  bf16*  Qb  = (bf16*)(ws + off_qb);
  bf16*  AV  = (bf16*)(ws + off_av);
  bf16*  VT  = (bf16*)(ws + off_vt);
  float* KVS = (float*)(ws + off_kvs);
  bf16*  BAV = (bf16*)(ws + off_bav);

  // prep
  k_prep_w4<<<dim3(32, 32, 4), 256, 0, stream>>>(Wq, Wk, Wv, Wo, WQT, WKT, WVT, WOT);
  k_init_vt<<<2048, 256, 0, stream>>>(VT);
  (void)hipMemsetAsync(KVS, 0, 1310720ull, stream);

  // fused cvt + all three projections, one z-grid dispatch (no inter-dispatch
  // drains; z=0 -> v, z=1 -> k, z=2 -> q)
  k_projf3<<<dim3(64, 4, 3), 512, 0, stream>>>(query, key, value,
                                               WQT, WKT, WVT,
                                               bq, bk, bvp,
                                               Qb, KT, VT);

  // state + normalizer
  k_kvs<<<dim3(16, 64), 256, 0, stream>>>(KT, VT, KVS);
  k_kvs_t<<<64, 256, 0, stream>>>(KVS, BAV);

  // attention readout + normalization
  k_av<<<dim3(32, 64), 256, 0, stream>>>(Qb, BAV, AV);

  // output projection
  k_gemm256<<<dim3(64, 4), 512, 0, stream>>>(AV, WOT, bo, out);
}

// Round 14
// 241.214 us; speedup vs baseline: 4.1671x; 1.0298x over previous
//
#include <hip/hip_runtime.h>
#include <stdint.h>

// ---------------------------------------------------------------------------
// Linear (kernelized) attention, B=4 L=4096 D=1024 H=16 M=64, fp32 in/out.
//   1. k_prep   : ONE dispatch (32,32,6): z<4 weight transposes -> bf16
//                 WT[out][in]; z==4 vt rows 64..79 init (row 64 = ones);
//                 z==5 KVS zero.
//   2. k_projf3 : ONE z-grid dispatch (64,4,3) = {v,k,q}.  FUSED fp32->bf16 +
//                 256x256/BK=64 MFMA GEMM (2-barrier loop): A reg-staged from
//                 fp32 X (NT loads, cvt, swizzled ds_write; next tile's loads
//                 issued under compute = T14), B via gload16 w/ pre-swizzled
//                 source (T2).  128 KiB LDS, launch_bounds(512,2) -- do NOT
//                 raise the occupancy bound (round-11: (512,4) caps VGPR at
//                 128 -> accumulator spill -> 4x slower).
//   3. k_gemm256: 8-phase GEMM: out = avn.WoT + bo (fp32)
//   4. k_kvs    : per (b,h) kvs[64 m][80 d'] += kt . vt^T  (fp32 atomics)
//   5. k_kvs_t  : kvs fp32 -> bav bf16 [bh][80][64] (transpose, 256 blocks)
//   6. k_av     : C[l][80] = q . bav^T; col 64 = norm; avn = C/norm (bf16)
// Structural ceiling notes (rounds 5-13): all GEMM schedules converge to
// ~650-860 TF at this K=1024 shape (MfmaUtil 19-23%, conflicts 0); 256^2
// tile admits only 1 block/CU (register geometry); kvs/av near HBM floors.
// ---------------------------------------------------------------------------

typedef __bf16 bf16;
typedef __bf16 bf16x4 __attribute__((ext_vector_type(4)));
typedef __bf16 bf16x8 __attribute__((ext_vector_type(8)));
typedef float f32x4 __attribute__((ext_vector_type(4)));

#define MFMA_(a, b, c) __builtin_amdgcn_mfma_f32_16x16x32_bf16((a), (b), (c), 0, 0, 0)

static constexpr int BB   = 4;
static constexpr int LSEQ = 4096;
static constexpr int DIM  = 1024;   // D == H*M
static constexpr int HH   = 16;
static constexpr float EPSF = 0.001f;

// ---- async global->LDS, 16B per lane, wave-uniform LDS base ---------------
__device__ __forceinline__ void gload16(bf16* lds, const bf16* g) {
  __builtin_amdgcn_global_load_lds(
      (const __attribute__((address_space(1))) void*)g,
      (__attribute__((address_space(3))) void*)lds, 16, 0, 0);
}

// ---------------- merged prep: transposes + vt-init + kvs-zero -------------
__global__ void k_prep(const float* __restrict__ W0, const float* __restrict__ W1,
                       const float* __restrict__ W2, const float* __restrict__ W3,
                       bf16* __restrict__ T0, bf16* __restrict__ T1,
                       bf16* __restrict__ T2, bf16* __restrict__ T3,
                       bf16* __restrict__ vt, float* __restrict__ kvs) {
  const int z = blockIdx.z;
  if (z < 4) {
    const float* W; bf16* T;
    switch (z) {
      case 0:  W = W0; T = T0; break;
      case 1:  W = W1; T = T1; break;
      case 2:  W = W2; T = T2; break;
      default: W = W3; T = T3; break;
    }
    __shared__ float t[32][33];
    const int tx = threadIdx.x & 31, ty = threadIdx.x >> 5;   // 32 x 8
    const int r0 = blockIdx.x * 32, c0 = blockIdx.y * 32;
#pragma unroll
    for (int j = 0; j < 32; j += 8)
      t[ty + j][tx] = W[(size_t)(r0 + ty + j) * DIM + c0 + tx];
    __syncthreads();
#pragma unroll
    for (int j = 0; j < 32; j += 8)
      T[(size_t)(c0 + ty + j) * DIM + r0 + tx] = (bf16)t[tx][ty + j];
  } else if (z == 4) {
    // vt rows 64..79: row 64 = ones, rest zeros.  524288 bf16x8 chunks,
    // 1024 blocks x 256 threads x 2 chunks.
    const int lb = blockIdx.y * 32 + blockIdx.x;
    const int c0i = lb * 256 + threadIdx.x;
#pragma unroll
    for (int half = 0; half < 2; ++half) {
      const int c = c0i + half * 262144;
      const int l8 = c & 511;
      const int r  = (c >> 9) & 15;
      const int bh = c >> 13;
      const bf16 val = (r == 0) ? (bf16)1.0f : (bf16)0.0f;
      bf16x8 o;
#pragma unroll
      for (int j = 0; j < 8; ++j) o[j] = val;
      *reinterpret_cast<bf16x8*>(vt + ((size_t)bh * 80 + 64 + r) * LSEQ + l8 * 8) = o;
    }
  } else {
    // zero KVS: 327680 floats = 81920 f32x4
    const int lb = blockIdx.y * 32 + blockIdx.x;
    const int idx = lb * 256 + threadIdx.x;
    if (idx < 81920) {
      f32x4 zz = {0.f, 0.f, 0.f, 0.f};
      *reinterpret_cast<f32x4*>(kvs + (size_t)idx * 4) = zz;
    }
  }
}

// ===========================================================================
// k_projf3: fused cvt + projection GEMM, all three projections in one
// z-grid dispatch.  256x256 tile, BK=64, 8 waves, single-buffered 2-barrier
// K-loop, 128 KiB LDS (1 block/CU).
// ===========================================================================
__global__ __launch_bounds__(512, 2) void k_projf3(
    const float* __restrict__ Xq, const float* __restrict__ Xk, const float* __restrict__ Xv,
    const bf16* __restrict__ WQT, const bf16* __restrict__ WKT, const bf16* __restrict__ WVT,
    const float* __restrict__ bq, const float* __restrict__ bk, const float* __restrict__ bv,
    bf16* __restrict__ Qb, bf16* __restrict__ KT, bf16* __restrict__ VT) {
  __shared__ __align__(16) bf16 SH[65536];      // 128 KiB (staging 64K + epi)
  bf16* As = SH;                                // 16384 elems: A tile 256x64
  bf16* Bs = SH + 16384;                        // 16384 elems: B tile 256x64
  const int mode = 2 - (int)blockIdx.z;         // z=0 -> v(2), z=1 -> k(1), z=2 -> q(0)
  const float* X    = (mode == 0) ? Xq  : (mode == 1) ? Xk  : Xv;
  const bf16*  WT   = (mode == 0) ? WQT : (mode == 1) ? WKT : WVT;
  const float* bias = (mode == 0) ? bq  : (mode == 1) ? bk  : bv;
  bf16*        outp = (mode == 0) ? Qb  : (mode == 1) ? KT  : VT;

  const int tid = threadIdx.x;
  const int lane = tid & 63, w = tid >> 6;      // 8 waves
  const int wm = w >> 2, wn = w & 3;            // 2 x 4 wave grid
  const int lr = lane & 15, lk = (lane >> 4) & 3;
  const int n0 = blockIdx.x * 256, c0 = blockIdx.y * 256;
  const int swz = (lr & 7) * 8;
  const int col0 = (lk * 8) ^ swz;
  const int col1 = (lk * 8 + 32) ^ swz;
  const int srow = lane >> 3;
  const int scol = (((lane & 7) ^ ((lane >> 3) & 7)) * 8);
  const float* Xb = X + (size_t)n0 * DIM;
  const bf16* Bb = WT + (size_t)c0 * DIM;

  f32x4 acc[8][4] = {};
  f32x4 af[8];

  // prologue: A tile 0 -> regs
#pragma unroll
  for (int j = 0; j < 8; ++j) {
    const int idx = tid + j * 512, row = idx >> 4, c4 = idx & 15;
    af[j] = __builtin_nontemporal_load(
        reinterpret_cast<const f32x4*>(Xb + (size_t)row * DIM + c4 * 4));
  }

  for (int ks = 0; ks < 16; ++ks) {
    const int k0 = ks * 64;
    __syncthreads();                            // LDS free (prev reads done)
    // stage B tile ks (4 gload16 per wave)
#pragma unroll
    for (int rr = 0; rr < 4; ++rr) {
      const int row = (rr * 8 + w) * 8 + srow;
      gload16(Bs + (rr * 8 + w) * 512, Bb + (size_t)row * DIM + k0 + scol);
    }
    // write A tile ks from regs (fp32 -> bf16, swizzled)
#pragma unroll
    for (int j = 0; j < 8; ++j) {
      const int idx = tid + j * 512, row = idx >> 4, c4 = idx & 15;
      bf16x4 o;
      o[0] = (bf16)af[j][0]; o[1] = (bf16)af[j][1];
      o[2] = (bf16)af[j][2]; o[3] = (bf16)af[j][3];
      *reinterpret_cast<bf16x4*>(
          &As[row * 64 + ((((c4 >> 1) ^ (row & 7)) << 3) | ((c4 & 1) << 2))]) = o;
    }
    __syncthreads();                            // drains B vmcnt + A writes
    // issue next A tile's loads (fly under the MFMA block = T14)
    if (ks < 15) {
#pragma unroll
      for (int j = 0; j < 8; ++j) {
        const int idx = tid + j * 512, row = idx >> 4, c4 = idx & 15;
        af[j] = __builtin_nontemporal_load(
            reinterpret_cast<const f32x4*>(Xb + (size_t)row * DIM + k0 + 64 + c4 * 4));
      }
    }
    // compute: 64 MFMA
    bf16x8 a[8][2], b[4][2];
#pragma unroll
    for (int f = 0; f < 8; ++f) {
      a[f][0] = *reinterpret_cast<const bf16x8*>(&As[(wm * 128 + f * 16 + lr) * 64 + col0]);
      a[f][1] = *reinterpret_cast<const bf16x8*>(&As[(wm * 128 + f * 16 + lr) * 64 + col1]);
    }
#pragma unroll
    for (int cb = 0; cb < 4; ++cb) {
      b[cb][0] = *reinterpret_cast<const bf16x8*>(&Bs[(wn * 64 + cb * 16 + lr) * 64 + col0]);
      b[cb][1] = *reinterpret_cast<const bf16x8*>(&Bs[(wn * 64 + cb * 16 + lr) * 64 + col1]);
    }
#pragma unroll
    for (int kk = 0; kk < 2; ++kk)
#pragma unroll
      for (int f = 0; f < 8; ++f)
#pragma unroll
        for (int cb = 0; cb < 4; ++cb)
          acc[f][cb] = MFMA_(a[f][kk], b[cb][kk], acc[f][cb]);
  }

  // ---------------- epilogue (LDS-transpose, coalesced stores) --------------
  float bvv[4];
#pragma unroll
  for (int cb = 0; cb < 4; ++cb) bvv[cb] = bias[c0 + wn * 64 + cb * 16 + lr];
  const int bidx = n0 >> 12;
  const int l0 = n0 & (LSEQ - 1);

  if (mode == 0) {
    __syncthreads();
#pragma unroll
    for (int f = 0; f < 8; ++f)
#pragma unroll
      for (int cb = 0; cb < 4; ++cb) {
        const int cl = wn * 64 + cb * 16 + lr;
#pragma unroll
        for (int r = 0; r < 4; ++r) {
          float x = acc[f][cb][r] + bvv[cb];
          x = fmaxf(x, 0.f) + EPSF;
          const int ll = wm * 128 + f * 16 + lk * 4 + r;
          SH[ll * 256 + ((((cl >> 3) ^ (ll & 7)) << 3) | (cl & 7))] = (bf16)x;
        }
      }
    __syncthreads();
#pragma unroll
    for (int it = 0; it < 16; ++it) {
      const int chunk = it * 512 + tid;
      const int row = chunk >> 5, blk = chunk & 31;
      const bf16x8 v = *reinterpret_cast<const bf16x8*>(&SH[row * 256 + ((blk ^ (row & 7)) << 3)]);
      *reinterpret_cast<bf16x8*>(outp + (size_t)(n0 + row) * DIM + c0 + blk * 8) = v;
    }
  } else {
    __syncthreads();
#pragma unroll
    for (int f = 0; f < 8; ++f)
#pragma unroll
      for (int cb = 0; cb < 4; ++cb) {
        const int cl = wn * 64 + cb * 16 + lr;
        const int ll = wm * 128 + f * 16 + lk * 4;
        bf16x4 o;
#pragma unroll
        for (int r = 0; r < 4; ++r) {
          float x = acc[f][cb][r] + bvv[cb];
          if (mode == 1) x = fmaxf(x, 0.f) + EPSF;
          o[r] = (bf16)x;
        }
        *reinterpret_cast<bf16x4*>(
            &SH[cl * 256 + ((((ll >> 3) ^ (cl & 7)) << 3) | (ll & 7))]) = o;
      }
    __syncthreads();
#pragma unroll
    for (int it = 0; it < 16; ++it) {
      const int chunk = it * 512 + tid;
      const int row = chunk >> 5, blk = chunk & 31;   // row = local c
      const bf16x8 v = *reinterpret_cast<const bf16x8*>(&SH[row * 256 + ((blk ^ (row & 7)) << 3)]);
      const int cg = c0 + row;
      size_t rowbase;
      if (mode == 1) rowbase = (size_t)bidx * 1024 + cg;                           // kt [b][c][L]
      else           rowbase = ((size_t)(bidx * HH + (cg >> 6)) * 80 + (cg & 63)); // vt [b][h][80][L]
      *reinterpret_cast<bf16x8*>(outp + rowbase * LSEQ + l0 + blk * 8) = v;
    }
  }
}

// ===========================================================================
// k_gemm256 (8-phase): out = A . WT^T + bias  (fp32)
// ===========================================================================
__device__ __forceinline__ void stage_half(bf16* As0, bf16* Bs0,
                                           const bf16* Ab, const bf16* Bb,
                                           int h, int w, int srow, int scol) {
  const int t = h >> 2, reg = h & 3, buf = t & 1;
  bf16* lds = ((reg < 2) ? As0 : Bs0) + buf * 16384 + (reg & 1) * 8192;
  const bf16* g = (reg < 2) ? Ab : Bb;
  const int rbase = (reg & 1) * 128;
#pragma unroll
  for (int rr = 0; rr < 2; ++rr) {
    const int row = rbase + (rr * 8 + w) * 8 + srow;
    gload16(lds + (rr * 8 + w) * 512, g + (size_t)row * DIM + t * 64 + scol);
  }
}

#define LDA(d, g, f)                                                                              \
  a[d][0] = *reinterpret_cast<const bf16x8*>(&As0[(g) * 16384 + (wm * 128 + (f) * 16 + lr) * 64 + col0]); \
  a[d][1] = *reinterpret_cast<const bf16x8*>(&As0[(g) * 16384 + (wm * 128 + (f) * 16 + lr) * 64 + col1]);
#define LDB(d, g, c)                                                                              \
  b[d][0] = *reinterpret_cast<const bf16x8*>(&Bs0[(g) * 16384 + (wn * 64 + (c) * 16 + lr) * 64 + col0]); \
  b[d][1] = *reinterpret_cast<const bf16x8*>(&Bs0[(g) * 16384 + (wn * 64 + (c) * 16 + lr) * 64 + col1]);
#define MM(fi, ci, fo, co)                                                                        \
  acc[fo][co] = MFMA_(a[fi][0], b[ci][0], acc[fo][co]);                                           \
  acc[fo][co] = MFMA_(a[fi][1], b[ci][1], acc[fo][co]);

#define PHASE(g, q, pidx)                                                                         \
  {                                                                                               \
    if ((q) == 0) { LDA(0, g, 0) LDA(1, g, 1) LDA(2, g, 2) LDA(3, g, 3)                           \
                    LDB(0, g, 0) LDB(1, g, 1) }                                                   \
    else if ((q) == 1) { LDB(0, g, 2) LDB(1, g, 3) }                                              \
    else if ((q) == 2) { LDA(0, g, 4) LDA(1, g, 5) LDA(2, g, 6) LDA(3, g, 7) }                    \
    else { LDB(0, g, 0) LDB(1, g, 1) }                                                            \
    const int hh = 8 * i + 5 + (pidx);                                                            \
    if (hh < 64) stage_half(As0, Bs0, Ab, Bb, hh, w, srow, scol);                                 \
    if ((pidx) == 3 || (pidx) == 7) {                                                             \
      if (i < 7) { asm volatile("s_waitcnt vmcnt(2)" ::: "memory"); }                             \
      else       { asm volatile("s_waitcnt vmcnt(0)" ::: "memory"); }                             \
    }                                                                                             \
    __builtin_amdgcn_sched_barrier(0);                                                            \
    __builtin_amdgcn_s_barrier();                                                                 \
    __builtin_amdgcn_sched_barrier(0);                                                            \
    __builtin_amdgcn_s_setprio(1);                                                                \
    if ((q) == 0) { MM(0, 0, 0, 0) MM(1, 0, 1, 0) MM(2, 0, 2, 0) MM(3, 0, 3, 0)                   \
                    MM(0, 1, 0, 1) MM(1, 1, 1, 1) MM(2, 1, 2, 1) MM(3, 1, 3, 1) }                 \
    else if ((q) == 1) { MM(0, 0, 0, 2) MM(1, 0, 1, 2) MM(2, 0, 2, 2) MM(3, 0, 3, 2)              \
                         MM(0, 1, 0, 3) MM(1, 1, 1, 3) MM(2, 1, 2, 3) MM(3, 1, 3, 3) }            \
    else if ((q) == 2) { MM(0, 0, 4, 2) MM(1, 0, 5, 2) MM(2, 0, 6, 2) MM(3, 0, 7, 2)              \
                         MM(0, 1, 4, 3) MM(1, 1, 5, 3) MM(2, 1, 6, 3) MM(3, 1, 7, 3) }            \
    else { MM(0, 0, 4, 0) MM(1, 0, 5, 0) MM(2, 0, 6, 0) MM(3, 0, 7, 0)                            \
           MM(0, 1, 4, 1) MM(1, 1, 5, 1) MM(2, 1, 6, 1) MM(3, 1, 7, 1) }                          \
    __builtin_amdgcn_s_setprio(0);                                                                \
    __builtin_amdgcn_sched_barrier(0);                                                            \
    __builtin_amdgcn_s_barrier();                                                                 \
    __builtin_amdgcn_sched_barrier(0);                                                            \
  }

__global__ __launch_bounds__(512, 2) void k_gemm256(const bf16* __restrict__ X,
                                                    const bf16* __restrict__ WT,
                                                    const float* __restrict__ bias,
                                                    float* __restrict__ outp) {
  __shared__ __align__(16) bf16 SH[65536];
  bf16* As0 = SH;
  bf16* Bs0 = SH + 32768;
  const int tid = threadIdx.x;
  const int lane = tid & 63, w = tid >> 6;
  const int wm = w >> 2, wn = w & 3;
  const int lr = lane & 15, lk = (lane >> 4) & 3;
  const int n0 = blockIdx.x * 256, c0 = blockIdx.y * 256;
  const int swz = (lr & 7) * 8;
  const int col0 = (lk * 8) ^ swz;
  const int col1 = (lk * 8 + 32) ^ swz;
  const int srow = lane >> 3;
  const int scol = (((lane & 7) ^ ((lane >> 3) & 7)) * 8);
  const bf16* Ab = X + (size_t)n0 * DIM;
  const bf16* Bb = WT + (size_t)c0 * DIM;

  f32x4 acc[8][4] = {};
  bf16x8 a[4][2], b[2][2];

#pragma unroll
  for (int h = 0; h < 5; ++h) stage_half(As0, Bs0, Ab, Bb, h, w, srow, scol);
  asm volatile("s_waitcnt vmcnt(2)" ::: "memory");
  __builtin_amdgcn_sched_barrier(0);
  __builtin_amdgcn_s_barrier();
  __builtin_amdgcn_sched_barrier(0);

  for (int i = 0; i < 8; ++i) {
    PHASE(0, 0, 0) PHASE(0, 1, 1) PHASE(0, 2, 2) PHASE(0, 3, 3)
    PHASE(1, 0, 4) PHASE(1, 1, 5) PHASE(1, 2, 6) PHASE(1, 3, 7)
  }

  float bvv[4];
#pragma unroll
  for (int cb = 0; cb < 4; ++cb) bvv[cb] = bias[c0 + wn * 64 + cb * 16 + lr];
#pragma unroll
  for (int f = 0; f < 8; ++f)
#pragma unroll
    for (int cb = 0; cb < 4; ++cb) {
      const int c = c0 + wn * 64 + cb * 16 + lr;
#pragma unroll
      for (int r = 0; r < 4; ++r) {
        const int row = n0 + wm * 128 + f * 16 + lk * 4 + r;
        outp[(size_t)row * DIM + c] = acc[f][cb][r] + bvv[cb];
      }
    }
}
#undef PHASE
#undef MM
#undef LDB
#undef LDA

// ---------------- kvs: per (b,h) C[64 m][80 d'] = kt . vt^T over l ---------
__global__ __launch_bounds__(256, 2) void k_kvs(const bf16* __restrict__ kt,
                                                const bf16* __restrict__ vt,
                                                float* __restrict__ kvs) {
  const int tid = threadIdx.x, lane = tid & 63, wid = tid >> 6;
  const int lr = lane & 15, lk = lane >> 4;
  const int bh = blockIdx.y;
  const int lbase = blockIdx.x * 256;       // 16 l-slices of 256
  __shared__ bf16 As[64][64];
  __shared__ bf16 Bs[80][64];
  f32x4 acc[5] = {};
  const bf16* ktb = kt + (size_t)bh * 64 * LSEQ;
  const bf16* vtb = vt + (size_t)bh * 80 * LSEQ;

  for (int ks = 0; ks < 4; ++ks) {
    const int l0 = lbase + ks * 64;
    __syncthreads();
#pragma unroll
    for (int i = 0; i < 2; ++i) {
      const int e = i * 2048 + tid * 8;
      const int row = e >> 6, col = e & 63;
      *reinterpret_cast<bf16x8*>(&As[row][col]) =
          *reinterpret_cast<const bf16x8*>(ktb + (size_t)row * LSEQ + l0 + col);
    }
#pragma unroll
    for (int i = 0; i < 2; ++i) {
      const int e = i * 2048 + tid * 8;
      const int row = e >> 6, col = e & 63;
      *reinterpret_cast<bf16x8*>(&Bs[row][col]) =
          *reinterpret_cast<const bf16x8*>(vtb + (size_t)row * LSEQ + l0 + col);
    }
    if (tid < 128) {
      const int e = 4096 + tid * 8;
      const int row = e >> 6, col = e & 63;
      *reinterpret_cast<bf16x8*>(&Bs[row][col]) =
          *reinterpret_cast<const bf16x8*>(vtb + (size_t)row * LSEQ + l0 + col);
    }
    __syncthreads();
#pragma unroll
    for (int kk = 0; kk < 2; ++kk) {
      const bf16x8 af = *reinterpret_cast<const bf16x8*>(&As[wid * 16 + lr][kk * 32 + lk * 8]);
#pragma unroll
      for (int cb = 0; cb < 5; ++cb) {
        const bf16x8 bfr = *reinterpret_cast<const bf16x8*>(&Bs[cb * 16 + lr][kk * 32 + lk * 8]);
        acc[cb] = MFMA_(af, bfr, acc[cb]);
      }
    }
  }
  float* kb = kvs + (size_t)bh * 64 * 80;
#pragma unroll
  for (int cb = 0; cb < 5; ++cb) {
    const int dcol = cb * 16 + lr;
#pragma unroll
    for (int r = 0; r < 4; ++r) {
      const int m = wid * 16 + lk * 4 + r;
      atomicAdd(kb + m * 80 + dcol, acc[cb][r]);
    }
  }
}

// ---------------- kvs fp32 [bh][64][80] -> bav bf16 [bh][80][64] -----------
__global__ void k_kvs_t(const float* __restrict__ kvs, bf16* __restrict__ bav) {
  const int bh = blockIdx.x >> 2, quarter = blockIdx.x & 3;
  const float* src = kvs + (size_t)bh * 5120;
  bf16* dst = bav + (size_t)bh * 5120;
  for (int i = quarter * 1280 + threadIdx.x; i < (quarter + 1) * 1280; i += 256) {
    const int dp = i >> 6, mm = i & 63;
    dst[i] = (bf16)src[mm * 80 + dp];
  }
}

// ---------------- av: per (b,h) C[128 l][80] = q . bav^T; normalize --------
__global__ __launch_bounds__(256, 2) void k_av(const bf16* __restrict__ q,
                                               const bf16* __restrict__ bav,
                                               bf16* __restrict__ avn) {
  const int tid = threadIdx.x, lane = tid & 63, wid = tid >> 6;
  const int lr = lane & 15, lk = lane >> 4;
  const int bh = blockIdx.y, b = bh >> 4, h = bh & 15;
  const int l0 = blockIdx.x * 128;
  __shared__ bf16 As[128][64];
  __shared__ bf16 Bs[80][64];
  __shared__ float nrm[128];

  const bf16* qb = q + ((size_t)b * LSEQ + l0) * DIM + h * 64;
#pragma unroll
  for (int i = 0; i < 4; ++i) {
    const int e = i * 2048 + tid * 8;
    const int row = e >> 6, col = e & 63;
    *reinterpret_cast<bf16x8*>(&As[row][col]) =
        *reinterpret_cast<const bf16x8*>(qb + (size_t)row * DIM + col);
  }
  const bf16* bb = bav + (size_t)bh * 5120;
#pragma unroll
  for (int i = 0; i < 2; ++i) {
    const int e = i * 2048 + tid * 8;
    const int row = e >> 6, col = e & 63;
    *reinterpret_cast<bf16x8*>(&Bs[row][col]) =
        *reinterpret_cast<const bf16x8*>(bb + row * 64 + col);
  }
  if (tid < 128) {
    const int e = 4096 + tid * 8;
    const int row = e >> 6, col = e & 63;
    *reinterpret_cast<bf16x8*>(&Bs[row][col]) =
        *reinterpret_cast<const bf16x8*>(bb + row * 64 + col);
  }
  __syncthreads();

  f32x4 acc[2][5] = {};
#pragma unroll
  for (int kk = 0; kk < 2; ++kk) {
    bf16x8 af[2];
    af[0] = *reinterpret_cast<const bf16x8*>(&As[wid * 32 + lr][kk * 32 + lk * 8]);
    af[1] = *reinterpret_cast<const bf16x8*>(&As[wid * 32 + 16 + lr][kk * 32 + lk * 8]);
#pragma unroll
    for (int cb = 0; cb < 5; ++cb) {
      const bf16x8 bfr = *reinterpret_cast<const bf16x8*>(&Bs[cb * 16 + lr][kk * 32 + lk * 8]);
      acc[0][cb] = MFMA_(af[0], bfr, acc[0][cb]);
      acc[1][cb] = MFMA_(af[1], bfr, acc[1][cb]);
    }
  }
  if (lr == 0) {
#pragma unroll
    for (int rb = 0; rb < 2; ++rb)
#pragma unroll
      for (int r = 0; r < 4; ++r)
        nrm[wid * 32 + rb * 16 + lk * 4 + r] = acc[rb][4][r];
  }
  __syncthreads();
  bf16* ob = avn + ((size_t)b * LSEQ + l0) * DIM + h * 64;
#pragma unroll
  for (int rb = 0; rb < 2; ++rb) {
#pragma unroll
    for (int cb = 0; cb < 4; ++cb) {
#pragma unroll
      for (int r = 0; r < 4; ++r) {
        const int row = wid * 32 + rb * 16 + lk * 4 + r;
        const float x = acc[rb][cb][r] / nrm[row];
        ob[(size_t)row * DIM + cb * 16 + lr] = (bf16)x;
      }
    }
  }
}

// ---------------------------------------------------------------------------
extern "C" void kernel_launch(void* const* d_in, const int* in_sizes, int n_in,
                              void* d_out, int out_size, void* d_ws, size_t ws_size,
                              hipStream_t stream) {
  const float* query = (const float*)d_in[0];
  const float* key   = (const float*)d_in[1];
  const float* value = (const float*)d_in[2];
  const float* Wq    = (const float*)d_in[3];
  const float* bq    = (const float*)d_in[4];
  const float* Wk    = (const float*)d_in[5];
  const float* bk    = (const float*)d_in[6];
  const float* Wv    = (const float*)d_in[7];
  const float* bvp   = (const float*)d_in[8];
  const float* Wo    = (const float*)d_in[9];
  const float* bo    = (const float*)d_in[10];
  float* out = (float*)d_out;
  char* ws = (char*)d_ws;

  const size_t off_wqt = 0;                        // 2 MB each
  const size_t off_wkt = off_wqt + (2u << 20);
  const size_t off_wvt = off_wkt + (2u << 20);
  const size_t off_wot = off_wvt + (2u << 20);
  const size_t off_kt  = off_wot + (2u << 20);     // 33,554,432
  const size_t off_qb  = off_kt  + 33554432ull;    // 33,554,432
  const size_t off_av  = off_qb  + 33554432ull;    // 33,554,432
  const size_t off_vt  = off_av  + 33554432ull;    // 41,943,040
  const size_t off_kvs = off_vt  + 41943040ull;    //  1,310,720 (fp32)
  const size_t off_bav = off_kvs + 1310720ull;     //    655,360
  const size_t total   = off_bav + 655360ull;      // ~146 MB
  if (ws_size < total) return;

  bf16*  WQT = (bf16*)(ws + off_wqt);
  bf16*  WKT = (bf16*)(ws + off_wkt);
  bf16*  WVT = (bf16*)(ws + off_wvt);
  bf16*  WOT = (bf16*)(ws + off_wot);
  bf16*  KT  = (bf16*)(ws + off_kt);
  bf16*  Qb  = (bf16*)(ws + off_qb);
  bf16*  AV  = (bf16*)(ws + off_av);
  bf16*  VT  = (bf16*)(ws + off_vt);
  float* KVS = (float*)(ws + off_kvs);
  bf16*  BAV = (bf16*)(ws + off_bav);

  // merged prep: 4 weight transposes + vt tail init + KVS zero
  k_prep<<<dim3(32, 32, 6), 256, 0, stream>>>(Wq, Wk, Wv, Wo,
                                              WQT, WKT, WVT, WOT, VT, KVS);

  // fused cvt + all three projections, one z-grid dispatch
  k_projf3<<<dim3(64, 4, 3), 512, 0, stream>>>(query, key, value,
                                               WQT, WKT, WVT,
                                               bq, bk, bvp,
                                               Qb, KT, VT);

  // state + normalizer
  k_kvs<<<dim3(16, 64), 256, 0, stream>>>(KT, VT, KVS);
  k_kvs_t<<<256, 256, 0, stream>>>(KVS, BAV);

  // attention readout + normalization
  k_av<<<dim3(32, 64), 256, 0, stream>>>(Qb, BAV, AV);

  // output projection
  k_gemm256<<<dim3(64, 4), 512, 0, stream>>>(AV, WOT, bo, out);
}